// Round 3
// baseline (43221.835 us; speedup 1.0000x reference)
//
#include <hip/hip_runtime.h>

typedef unsigned short u16;
typedef __attribute__((ext_vector_type(8))) short short8;
typedef __attribute__((ext_vector_type(4))) float f32x4;

#define B_ 2048
#define T_ 64
#define I_ 64
#define H_ 1024
#define G_ 4096

__device__ __forceinline__ float bf2f(u16 v) {
  union { float f; unsigned u; } x; x.u = ((unsigned)v) << 16; return x.f;
}
__device__ __forceinline__ u16 f2bf(float f) {
  union { float f; unsigned u; } x; x.f = f;
  unsigned r = x.u + 0x7fffu + ((x.u >> 16) & 1u);
  return (u16)(r >> 16);
}
__device__ __forceinline__ float sigm(float x) { return 1.0f / (1.0f + __expf(-x)); }
__device__ __forceinline__ float tanh_(float x) { return 1.0f - 2.0f / (__expf(2.0f * x) + 1.0f); }

__device__ __forceinline__ void async_copy16(const u16* g, u16* l) {
  __builtin_amdgcn_global_load_lds((__attribute__((address_space(1))) void*)(void*)g,
                                   (__attribute__((address_space(3))) void*)l, 16, 0, 0);
}

// -------------------- setup kernels --------------------

// x [B,T,I] fp32 -> xT [T,B,I] bf16
__global__ void k_transpose_x(const float* __restrict__ x, u16* __restrict__ xT) {
  int idx = blockIdx.x * 256 + threadIdx.x;  // over B*T*I = 8388608
  if (idx >= B_ * T_ * I_) return;
  int i = idx & 63;
  int t = (idx >> 6) & 63;
  int b = idx >> 12;
  xT[((size_t)t * B_ + b) * I_ + i] = f2bf(x[idx]);
}

// Build BT [4096][K] bf16: rows are permuted output cols n' = 4*unit + gate,
// k<K0 from U (recurrent), k>=K0 from W (input). Orig col j = gate*1024 + unit.
__global__ void k_build_bt(const float* __restrict__ U, const float* __restrict__ W,
                           u16* __restrict__ BT, int K0, int K) {
  int n = blockIdx.y;
  int k = blockIdx.x * 256 + threadIdx.x;
  if (k >= K) return;
  int j = (n & 3) * 1024 + (n >> 2);
  float v = (k < K0) ? U[(size_t)k * G_ + j] : W[(size_t)(k - K0) * G_ + j];
  BT[(size_t)n * K + k] = f2bf(v);
}

__global__ void k_build_bias(const float* __restrict__ b1, const float* __restrict__ b2,
                             const float* __restrict__ bd1, const float* __restrict__ bd2,
                             const float* __restrict__ d1W,
                             float* __restrict__ p1, float* __restrict__ p2,
                             float* __restrict__ pd1, float* __restrict__ pd2,
                             float* __restrict__ pd1W) {
  int n = blockIdx.x * 256 + threadIdx.x;
  if (n >= G_) return;
  int j = (n & 3) * 1024 + (n >> 2);
  p1[n] = b1[j]; p2[n] = b2[j]; pd1[n] = bd1[j]; pd2[n] = bd2[j];
  pd1W[n] = d1W[j];
}

// -------------------- fused GEMM + LSTM cell --------------------

struct GemmP {
  const u16* A0; int lda0, kt0;
  const u16* A1; int lda1, kt1;
  const u16* BT; int ldb;
  const float* biasp;
  const float* evec;
  const float* escal; int estride;
  float* cst; u16* hout;
};

// z[m, n'] = sum_k A[m,k] * BT[n',k]  (A = [A0 seg | A1 seg] along K)
// then per (m, unit): i,f,g,o = z cols 4u..4u+3 (+bias, + optional gen*d1_W),
// c = f*c + i*g; h = o*tanh(c) -> hout bf16.
__device__ __forceinline__ void gemm_body(u16* smem, const GemmP& p, int m0, int n0) {
  const int tid = threadIdx.x;
  const int lane = tid & 63;
  const int w = tid >> 6;
  const int KT = p.kt0 + p.kt1;

  // staging: thread covers LDS row rs = s*32 + tid/8, chunk c = tid&7;
  // global chunk fetched = c ^ (rs&7)  (XOR swizzle applied on the global side)
  const int r_ = tid >> 3, c_ = tid & 7;
  const u16* pA0[4]; const u16* pA1[4]; const u16* pB[4];
#pragma unroll
  for (int s = 0; s < 4; ++s) {
    int rs = (s << 5) + r_;
    int ch = (c_ ^ (rs & 7)) << 3;
    pA0[s] = p.A0 + (size_t)(m0 + rs) * p.lda0 + ch;
    pA1[s] = p.A1 ? (p.A1 + (size_t)(m0 + rs) * p.lda1 + ch) : pA0[s];
    pB[s] = p.BT + (size_t)(n0 + rs) * p.ldb + ch;
  }
  u16* ldsA = smem + (w << 9);
  u16* ldsB = smem + 8192 + (w << 9);

  f32x4 acc[4][4];
#pragma unroll
  for (int i = 0; i < 4; ++i)
#pragma unroll
    for (int j = 0; j < 4; ++j) acc[i][j] = (f32x4){0.f, 0.f, 0.f, 0.f};

  const int wm = (w >> 1) << 6, wn = (w & 1) << 6;
  const int q = lane >> 4, l15 = lane & 15, l7 = lane & 7;
  int aoffr[4], boffr[4];
#pragma unroll
  for (int i = 0; i < 4; ++i) {
    aoffr[i] = (wm + (i << 4) + l15) << 6;
    boffr[i] = 8192 + ((wn + (i << 4) + l15) << 6);
  }

  for (int kt = 0; kt < KT; ++kt) {
    __syncthreads();  // previous tile's compute done
    bool seg0 = (kt < p.kt0);
#pragma unroll
    for (int s = 0; s < 4; ++s) {
      const u16* ga = seg0 ? (pA0[s] + (size_t)kt * 64)
                           : (pA1[s] + (size_t)(kt - p.kt0) * 64);
      async_copy16(ga, ldsA + (s << 11));
      async_copy16(pB[s] + (size_t)kt * 64, ldsB + (s << 11));
    }
    __syncthreads();  // drains vmcnt(0) -> LDS visible
#pragma unroll
    for (int ks = 0; ks < 2; ++ks) {
      const int sw = ((((ks << 2) + q) ^ l7) << 3);
      short8 af[4], bfr[4];
#pragma unroll
      for (int i = 0; i < 4; ++i) {
        af[i] = *(const short8*)&smem[aoffr[i] + sw];
        bfr[i] = *(const short8*)&smem[boffr[i] + sw];
      }
#pragma unroll
      for (int i = 0; i < 4; ++i)
#pragma unroll
        for (int j = 0; j < 4; ++j)
          acc[i][j] = __builtin_amdgcn_mfma_f32_16x16x32_bf16(af[i], bfr[j], acc[i][j], 0, 0, 0);
    }
  }

  // ---- fused LSTM-cell epilogue (LDS reshuffle: C-layout -> per-lane 4 gates) ----
  __syncthreads();
  float* ep = (float*)smem + w * 1280;  // per-wave [64][20] fp32 region
  const int ul = lane & 3, ml = lane >> 2;
  const int ubase = (n0 >> 2) + (wn >> 2);
#pragma unroll 1
  for (int tj = 0; tj < 4; ++tj) {
#pragma unroll
    for (int ti = 0; ti < 4; ++ti)
#pragma unroll
      for (int v = 0; v < 4; ++v)
        ep[((ti << 4) + (q << 2) + v) * 20 + l15] = acc[ti][tj][v];
    __syncthreads();
#pragma unroll
    for (int pp = 0; pp < 4; ++pp) {
      int row = ml + (pp << 4);
      f32x4 z = *(const f32x4*)&ep[row * 20 + (ul << 2)];
      int gm = m0 + wm + row;
      int gu = ubase + (tj << 2) + ul;
      const f32x4 bb = *(const f32x4*)&p.biasp[gu << 2];
      z.x += bb.x; z.y += bb.y; z.z += bb.z; z.w += bb.w;
      if (p.evec) {  // d1: + gen[m] * d1_W[n']  (K=1 input folded here, fp32)
        float gs = p.escal[(size_t)gm * p.estride];
        const f32x4 ev = *(const f32x4*)&p.evec[gu << 2];
        z.x += gs * ev.x; z.y += gs * ev.y; z.z += gs * ev.z; z.w += gs * ev.w;
      }
      float ig = sigm(z.x), fg = sigm(z.y), gg = tanh_(z.z), og = sigm(z.w);
      size_t ci = ((size_t)gm << 10) + gu;
      float cn = fg * p.cst[ci] + ig * gg;
      p.cst[ci] = cn;
      p.hout[ci] = f2bf(og * tanh_(cn));
    }
    __syncthreads();
  }
}

// single-problem wrapper (pipeline prolog/epilog), grid (16,32), XCD-chunked swizzle
__global__ __launch_bounds__(256, 3) void k_gemm(GemmP p) {
  __shared__ u16 smem[16384];  // 32 KB
  int id = blockIdx.y * 16 + blockIdx.x;          // 512 blocks, 512%8==0 -> bijective
  int nid = ((id & 7) << 6) + (id >> 3);
  int bx = nid & 15, by = nid >> 4;
  gemm_body(smem, p, bx << 7, by << 7);
}

// paired wrapper: two INDEPENDENT problems interleaved tile-by-tile (phase diversity
// between co-resident blocks) + XCD-chunked swizzle. grid (32,32) = 1024 blocks.
__global__ __launch_bounds__(256, 3) void k_gemm2(GemmP pa, GemmP pb) {
  __shared__ u16 smem[16384];  // 32 KB
  int id = blockIdx.y * 32 + blockIdx.x;          // 1024 blocks, 1024%8==0 -> bijective
  int nid = ((id & 7) << 7) + (id >> 3);
  int bx = nid & 31, by = nid >> 5;
  const GemmP& p = (bx & 1) ? pb : pa;
  gemm_body(smem, p, (bx >> 1) << 7, by << 7);
}

// -------------------- small kernels --------------------

// g3: LSTM with H=1. One wave per batch row.
__global__ void k_g3(const u16* __restrict__ h2, const float* __restrict__ W,
                     const float* __restrict__ Uv, const float* __restrict__ bv,
                     float* __restrict__ c3, float* __restrict__ h3,
                     float* __restrict__ gen, int t) {
  int b = blockIdx.x * 4 + (threadIdx.x >> 6);
  int lane = threadIdx.x & 63;
  float a0 = 0.f, a1 = 0.f, a2 = 0.f, a3 = 0.f;
  for (int k = lane; k < H_; k += 64) {
    float hv = bf2f(h2[((size_t)b << 10) + k]);
    const f32x4 wv = *(const f32x4*)&W[k << 2];
    a0 += hv * wv.x; a1 += hv * wv.y; a2 += hv * wv.z; a3 += hv * wv.w;
  }
  for (int off = 32; off; off >>= 1) {
    a0 += __shfl_down(a0, off);
    a1 += __shfl_down(a1, off);
    a2 += __shfl_down(a2, off);
    a3 += __shfl_down(a3, off);
  }
  if (lane == 0) {
    float hp = h3[b];
    float zi = a0 + hp * Uv[0] + bv[0];
    float zf = a1 + hp * Uv[1] + bv[1];
    float zg = a2 + hp * Uv[2] + bv[2];
    float zo = a3 + hp * Uv[3] + bv[3];
    float cn = sigm(zf) * c3[b] + sigm(zi) * tanh_(zg);
    c3[b] = cn;
    float hn = sigm(zo) * tanh_(cn);
    h3[b] = hn;
    gen[b * T_ + t] = hn;
  }
}

// final dense: disc[b,t] = hd2[b,:] . do_W + do_b
__global__ void k_dense(const u16* __restrict__ hd2, const float* __restrict__ wv,
                        const float* __restrict__ bs, float* __restrict__ disc, int t) {
  int b = blockIdx.x * 4 + (threadIdx.x >> 6);
  int lane = threadIdx.x & 63;
  float a = 0.f;
  for (int k = lane; k < H_; k += 64)
    a += bf2f(hd2[((size_t)b << 10) + k]) * wv[k];
  for (int off = 32; off; off >>= 1) a += __shfl_down(a, off);
  if (lane == 0) disc[b * T_ + t] = a + bs[0];
}

// merged steady-state small kernel: blocks 0..511 -> g3[t+1], 512..1023 -> dense[t]
__global__ void k_small(const u16* __restrict__ h2s, const float* __restrict__ W,
                        const float* __restrict__ Uv, const float* __restrict__ bv,
                        float* __restrict__ c3, float* __restrict__ h3,
                        float* __restrict__ gen, int tg,
                        const u16* __restrict__ hd2s, const float* __restrict__ wv,
                        const float* __restrict__ bs, float* __restrict__ disc, int td) {
  int lane = threadIdx.x & 63;
  if (blockIdx.x < 512) {
    int b = blockIdx.x * 4 + (threadIdx.x >> 6);
    float a0 = 0.f, a1 = 0.f, a2 = 0.f, a3 = 0.f;
    for (int k = lane; k < H_; k += 64) {
      float hv = bf2f(h2s[((size_t)b << 10) + k]);
      const f32x4 wv4 = *(const f32x4*)&W[k << 2];
      a0 += hv * wv4.x; a1 += hv * wv4.y; a2 += hv * wv4.z; a3 += hv * wv4.w;
    }
    for (int off = 32; off; off >>= 1) {
      a0 += __shfl_down(a0, off);
      a1 += __shfl_down(a1, off);
      a2 += __shfl_down(a2, off);
      a3 += __shfl_down(a3, off);
    }
    if (lane == 0) {
      float hp = h3[b];
      float zi = a0 + hp * Uv[0] + bv[0];
      float zf = a1 + hp * Uv[1] + bv[1];
      float zg = a2 + hp * Uv[2] + bv[2];
      float zo = a3 + hp * Uv[3] + bv[3];
      float cn = sigm(zf) * c3[b] + sigm(zi) * tanh_(zg);
      c3[b] = cn;
      float hn = sigm(zo) * tanh_(cn);
      h3[b] = hn;
      gen[b * T_ + tg] = hn;
    }
  } else {
    int b = (blockIdx.x - 512) * 4 + (threadIdx.x >> 6);
    float a = 0.f;
    for (int k = lane; k < H_; k += 64)
      a += bf2f(hd2s[((size_t)b << 10) + k]) * wv[k];
    for (int off = 32; off; off >>= 1) a += __shfl_down(a, off);
    if (lane == 0) disc[b * T_ + td] = a + bs[0];
  }
}

// -------------------- launcher --------------------
// Software pipeline: generator chain at step t+1 runs concurrently (same launch)
// with discriminator chain at step t. 3 launches/step instead of 6.
//   J1(t) = {g1[t+1], d1[t]}   J2(t) = {g2[t+1], d2[t]}   S(t) = {g3[t+1], dense[t]}

extern "C" void kernel_launch(void* const* d_in, const int* in_sizes, int n_in,
                              void* d_out, int out_size, void* d_ws, size_t ws_size,
                              hipStream_t stream) {
  const float* x   = (const float*)d_in[0];
  const float* g1W = (const float*)d_in[1];
  const float* g1U = (const float*)d_in[2];
  const float* g1b = (const float*)d_in[3];
  const float* g2W = (const float*)d_in[4];
  const float* g2U = (const float*)d_in[5];
  const float* g2b = (const float*)d_in[6];
  const float* g3W = (const float*)d_in[7];
  const float* g3U = (const float*)d_in[8];
  const float* g3b = (const float*)d_in[9];
  const float* d1W = (const float*)d_in[10];
  const float* d1U = (const float*)d_in[11];
  const float* d1b = (const float*)d_in[12];
  const float* d2W = (const float*)d_in[13];
  const float* d2U = (const float*)d_in[14];
  const float* d2b = (const float*)d_in[15];
  const float* doW = (const float*)d_in[16];
  const float* dob = (const float*)d_in[17];

  char* ws = (char*)d_ws;
  u16* xT    = (u16*)(ws + 0);            // 16,777,216
  u16* BT1   = (u16*)(ws + 16777216);     //  8,912,896  [4096][1088]
  u16* BT2   = (u16*)(ws + 25690112);     // 16,777,216  [4096][2048]
  u16* BTd1  = (u16*)(ws + 42467328);     //  8,388,608  [4096][1024]
  u16* BTd2  = (u16*)(ws + 50855936);     // 16,777,216  [4096][2048]
  float* pb1  = (float*)(ws + 67633152);
  float* pb2  = (float*)(ws + 67649536);
  float* pbd1 = (float*)(ws + 67665920);
  float* pbd2 = (float*)(ws + 67682304);
  float* pd1W = (float*)(ws + 67698688);
  const size_t Z0 = 67715072;             // zeroed region start
  float* c1  = (float*)(ws + Z0);
  float* c2  = (float*)(ws + Z0 + 8388608);
  float* cd1 = (float*)(ws + Z0 + 16777216);
  float* cd2 = (float*)(ws + Z0 + 25165824);
  u16* h1[2]  = {(u16*)(ws + Z0 + 33554432), (u16*)(ws + Z0 + 37748736)};
  u16* h2[2]  = {(u16*)(ws + Z0 + 41943040), (u16*)(ws + Z0 + 46137344)};
  u16* hd1[2] = {(u16*)(ws + Z0 + 50331648), (u16*)(ws + Z0 + 54525952)};
  u16* hd2[2] = {(u16*)(ws + Z0 + 58720256), (u16*)(ws + Z0 + 62914560)};
  float* c3 = (float*)(ws + Z0 + 67108864);
  float* h3 = (float*)(ws + Z0 + 67117056);
  const size_t ZBYTES = 67125248;

  // setup (re-done every launch: ws is poisoned before each timed call)
  k_transpose_x<<<32768, 256, 0, stream>>>(x, xT);
  k_build_bt<<<dim3(5, 4096), 256, 0, stream>>>(g1U, g1W, BT1, 1024, 1088);
  k_build_bt<<<dim3(8, 4096), 256, 0, stream>>>(g2U, g2W, BT2, 1024, 2048);
  k_build_bt<<<dim3(4, 4096), 256, 0, stream>>>(d1U, nullptr, BTd1, 1024, 1024);
  k_build_bt<<<dim3(8, 4096), 256, 0, stream>>>(d2U, d2W, BTd2, 1024, 2048);
  k_build_bias<<<16, 256, 0, stream>>>(g1b, g2b, d1b, d2b, d1W, pb1, pb2, pbd1, pbd2, pd1W);
  (void)hipMemsetAsync(ws + Z0, 0, ZBYTES, stream);

  float* gen = (float*)d_out;
  float* disc = gen + (size_t)B_ * T_;
  dim3 blk(256);
  dim3 grid1(16, 32), grid2(32, 32);

  // ---- prolog: g-chain step 0 (t=0: rp=0, wp=1) ----
  {
    GemmP pg1 = {h1[0], H_, 16, xT, I_, 1, BT1, 1088,
                 pb1, nullptr, nullptr, 0, c1, h1[1]};
    k_gemm<<<grid1, blk, 0, stream>>>(pg1);
    GemmP pg2 = {h2[0], H_, 16, h1[1], H_, 16, BT2, 2048,
                 pb2, nullptr, nullptr, 0, c2, h2[1]};
    k_gemm<<<grid1, blk, 0, stream>>>(pg2);
    k_g3<<<512, blk, 0, stream>>>(h2[1], g3W, g3U, g3b, c3, h3, gen, 0);
  }

  // ---- steady state: t = 0..62 ----
  for (int t = 0; t < 63; ++t) {
    int rg = (t + 1) & 1, wg = rg ^ 1;  // g-chain step t+1 parity
    int rd = t & 1, wd = rd ^ 1;        // d-chain step t parity
    // J1: g1[t+1] || d1[t]
    GemmP pg1 = {h1[rg], H_, 16, xT + (size_t)(t + 1) * B_ * I_, I_, 1, BT1, 1088,
                 pb1, nullptr, nullptr, 0, c1, h1[wg]};
    GemmP pd1 = {hd1[rd], H_, 16, nullptr, 0, 0, BTd1, 1024,
                 pbd1, pd1W, gen + t, T_, cd1, hd1[wd]};
    k_gemm2<<<grid2, blk, 0, stream>>>(pg1, pd1);
    // J2: g2[t+1] || d2[t]
    GemmP pg2 = {h2[rg], H_, 16, h1[wg], H_, 16, BT2, 2048,
                 pb2, nullptr, nullptr, 0, c2, h2[wg]};
    GemmP pd2 = {hd2[rd], H_, 16, hd1[wd], H_, 16, BTd2, 2048,
                 pbd2, nullptr, nullptr, 0, cd2, hd2[wd]};
    k_gemm2<<<grid2, blk, 0, stream>>>(pg2, pd2);
    // S: g3[t+1] || dense[t]
    k_small<<<1024, blk, 0, stream>>>(h2[wg], g3W, g3U, g3b, c3, h3, gen, t + 1,
                                      hd2[wd], doW, dob, disc, t);
  }

  // ---- epilog: d-chain step 63 (rd=1, wd=0) ----
  {
    GemmP pd1 = {hd1[1], H_, 16, nullptr, 0, 0, BTd1, 1024,
                 pbd1, pd1W, gen + 63, T_, cd1, hd1[0]};
    k_gemm<<<grid1, blk, 0, stream>>>(pd1);
    GemmP pd2 = {hd2[1], H_, 16, hd1[0], H_, 16, BTd2, 2048,
                 pbd2, nullptr, nullptr, 0, cd2, hd2[0]};
    k_gemm<<<grid1, blk, 0, stream>>>(pd2);
    k_dense<<<512, blk, 0, stream>>>(hd2[0], doW, dob, disc, 63);
  }
  (void)in_sizes; (void)n_in; (void)out_size; (void)ws_size;
}

// Round 5
// 41579.147 us; speedup vs baseline: 1.0395x; 1.0395x over previous
//
#include <hip/hip_runtime.h>

typedef unsigned short u16;
typedef __attribute__((ext_vector_type(8))) short short8;
typedef __attribute__((ext_vector_type(4))) float f32x4;

#define B_ 2048
#define T_ 64
#define I_ 64
#define H_ 1024
#define G_ 4096

__device__ __forceinline__ float bf2f(u16 v) {
  union { float f; unsigned u; } x; x.u = ((unsigned)v) << 16; return x.f;
}
__device__ __forceinline__ u16 f2bf(float f) {
  union { float f; unsigned u; } x; x.f = f;
  unsigned r = x.u + 0x7fffu + ((x.u >> 16) & 1u);
  return (u16)(r >> 16);
}
__device__ __forceinline__ float sigm(float x) { return 1.0f / (1.0f + __expf(-x)); }
__device__ __forceinline__ float tanh_(float x) { return 1.0f - 2.0f / (__expf(2.0f * x) + 1.0f); }

__device__ __forceinline__ void async_copy16(const u16* g, u16* l) {
  __builtin_amdgcn_global_load_lds((__attribute__((address_space(1))) void*)(void*)g,
                                   (__attribute__((address_space(3))) void*)l, 16, 0, 0);
}

// -------------------- setup kernels --------------------

// x [B,T,I] fp32 -> xT [T,B,I] bf16
__global__ void k_transpose_x(const float* __restrict__ x, u16* __restrict__ xT) {
  int idx = blockIdx.x * 256 + threadIdx.x;  // over B*T*I = 8388608
  if (idx >= B_ * T_ * I_) return;
  int i = idx & 63;
  int t = (idx >> 6) & 63;
  int b = idx >> 12;
  xT[((size_t)t * B_ + b) * I_ + i] = f2bf(x[idx]);
}

// Build BT [4096][K] bf16: rows are permuted output cols n' = 4*unit + gate,
// k<K0 from U (recurrent), k>=K0 from W (input). Orig col j = gate*1024 + unit.
__global__ void k_build_bt(const float* __restrict__ U, const float* __restrict__ W,
                           u16* __restrict__ BT, int K0, int K) {
  int n = blockIdx.y;
  int k = blockIdx.x * 256 + threadIdx.x;
  if (k >= K) return;
  int j = (n & 3) * 1024 + (n >> 2);
  float v = (k < K0) ? U[(size_t)k * G_ + j] : W[(size_t)(k - K0) * G_ + j];
  BT[(size_t)n * K + k] = f2bf(v);
}

__global__ void k_build_bias(const float* __restrict__ b1, const float* __restrict__ b2,
                             const float* __restrict__ bd1, const float* __restrict__ bd2,
                             const float* __restrict__ d1W,
                             float* __restrict__ p1, float* __restrict__ p2,
                             float* __restrict__ pd1, float* __restrict__ pd2,
                             float* __restrict__ pd1W) {
  int n = blockIdx.x * 256 + threadIdx.x;
  if (n >= G_) return;
  int j = (n & 3) * 1024 + (n >> 2);
  p1[n] = b1[j]; p2[n] = b2[j]; pd1[n] = bd1[j]; pd2[n] = bd2[j];
  pd1W[n] = d1W[j];
}

// -------------------- fused GEMM + LSTM cell --------------------

struct GemmP {
  const u16* A0; int lda0, kt0;
  const u16* A1; int lda1, kt1;
  const u16* BT; int ldb;
  const float* biasp;
  const float* evec;
  const float* escal; int estride;
  float* cst; u16* hout;
};

// z[m, n'] = sum_k A[m,k] * BT[n',k]  (A = [A0 seg | A1 seg] along K)
// then per (m, unit): i,f,g,o = z cols 4u..4u+3 (+bias, + optional gen*d1_W),
// c = f*c + i*g; h = o*tanh(c) -> hout bf16.
__device__ __forceinline__ void gemm_body(u16* smem, const GemmP& p, int m0, int n0) {
  const int tid = threadIdx.x;
  const int lane = tid & 63;
  const int w = tid >> 6;
  const int KT = p.kt0 + p.kt1;

  // staging: thread covers LDS row rs = s*32 + tid/8, chunk c = tid&7;
  // global chunk fetched = c ^ (rs&7)  (XOR swizzle applied on the global side)
  const int r_ = tid >> 3, c_ = tid & 7;
  const u16* pA0[4]; const u16* pA1[4]; const u16* pB[4];
#pragma unroll
  for (int s = 0; s < 4; ++s) {
    int rs = (s << 5) + r_;
    int ch = (c_ ^ (rs & 7)) << 3;
    pA0[s] = p.A0 + (size_t)(m0 + rs) * p.lda0 + ch;
    pA1[s] = p.A1 ? (p.A1 + (size_t)(m0 + rs) * p.lda1 + ch) : pA0[s];
    pB[s] = p.BT + (size_t)(n0 + rs) * p.ldb + ch;
  }
  u16* ldsA = smem + (w << 9);
  u16* ldsB = smem + 8192 + (w << 9);

  f32x4 acc[4][4];
#pragma unroll
  for (int i = 0; i < 4; ++i)
#pragma unroll
    for (int j = 0; j < 4; ++j) acc[i][j] = (f32x4){0.f, 0.f, 0.f, 0.f};

  const int wm = (w >> 1) << 6, wn = (w & 1) << 6;
  const int q = lane >> 4, l15 = lane & 15, l7 = lane & 7;
  int aoffr[4], boffr[4];
#pragma unroll
  for (int i = 0; i < 4; ++i) {
    aoffr[i] = (wm + (i << 4) + l15) << 6;
    boffr[i] = 8192 + ((wn + (i << 4) + l15) << 6);
  }

  for (int kt = 0; kt < KT; ++kt) {
    __syncthreads();  // previous tile's compute done
    bool seg0 = (kt < p.kt0);
#pragma unroll
    for (int s = 0; s < 4; ++s) {
      const u16* ga = seg0 ? (pA0[s] + (size_t)kt * 64)
                           : (pA1[s] + (size_t)(kt - p.kt0) * 64);
      async_copy16(ga, ldsA + (s << 11));
      async_copy16(pB[s] + (size_t)kt * 64, ldsB + (s << 11));
    }
    __syncthreads();  // drains vmcnt(0) -> LDS visible
#pragma unroll
    for (int ks = 0; ks < 2; ++ks) {
      const int sw = ((((ks << 2) + q) ^ l7) << 3);
      short8 af[4], bfr[4];
#pragma unroll
      for (int i = 0; i < 4; ++i) {
        af[i] = *(const short8*)&smem[aoffr[i] + sw];
        bfr[i] = *(const short8*)&smem[boffr[i] + sw];
      }
#pragma unroll
      for (int i = 0; i < 4; ++i)
#pragma unroll
        for (int j = 0; j < 4; ++j)
          acc[i][j] = __builtin_amdgcn_mfma_f32_16x16x32_bf16(af[i], bfr[j], acc[i][j], 0, 0, 0);
    }
  }

  // ---- fused LSTM-cell epilogue (LDS reshuffle: C-layout -> per-lane 4 gates) ----
  __syncthreads();
  float* ep = (float*)smem + w * 1280;  // per-wave [64][20] fp32 region
  const int ul = lane & 3, ml = lane >> 2;
  const int ubase = (n0 >> 2) + (wn >> 2);
#pragma unroll 1
  for (int tj = 0; tj < 4; ++tj) {
#pragma unroll
    for (int ti = 0; ti < 4; ++ti)
#pragma unroll
      for (int v = 0; v < 4; ++v)
        ep[((ti << 4) + (q << 2) + v) * 20 + l15] = acc[ti][tj][v];
    __syncthreads();
#pragma unroll
    for (int pp = 0; pp < 4; ++pp) {
      int row = ml + (pp << 4);
      f32x4 z = *(const f32x4*)&ep[row * 20 + (ul << 2)];
      int gm = m0 + wm + row;
      int gu = ubase + (tj << 2) + ul;
      const f32x4 bb = *(const f32x4*)&p.biasp[gu << 2];
      z.x += bb.x; z.y += bb.y; z.z += bb.z; z.w += bb.w;
      if (p.evec) {  // d1: + gen[m] * d1_W[n']  (K=1 input folded here, fp32)
        float gs = p.escal[(size_t)gm * p.estride];
        const f32x4 ev = *(const f32x4*)&p.evec[gu << 2];
        z.x += gs * ev.x; z.y += gs * ev.y; z.z += gs * ev.z; z.w += gs * ev.w;
      }
      float ig = sigm(z.x), fg = sigm(z.y), gg = tanh_(z.z), og = sigm(z.w);
      size_t ci = ((size_t)gm << 10) + gu;
      float cn = fg * p.cst[ci] + ig * gg;
      p.cst[ci] = cn;
      p.hout[ci] = f2bf(og * tanh_(cn));
    }
    __syncthreads();
  }
}

// single-problem wrapper (pipeline prolog/epilog), 512 blocks.
// XCD-local mapping: HW round-robins linear id across the 8 XCDs (id&7 = xcd).
// Each XCD gets 4 contiguous by (n-rows) x all 16 bx -> per-K-step live slice
// (A 256KB + B 64KB) is L2-resident; B fetched once chip-wide.
__global__ __launch_bounds__(256, 4) void k_gemm(GemmP p) {
  __shared__ u16 smem[16384];  // 32 KB
  int id = blockIdx.y * 16 + blockIdx.x;  // 512 blocks
  int xcd = id & 7, slot = id >> 3;       // slot in [0,64)
  int by = (xcd << 2) + (slot >> 4);      // 4 by per XCD
  int bx = slot & 15;
  gemm_body(smem, p, bx << 7, by << 7);
}

// paired wrapper: two INDEPENDENT problems. XCD parity selects the problem
// (4 XCDs each) so one XCD touches ONE problem's A/B only; within the XCD,
// a contiguous 8-wide by chunk x all 16 bx. Per-XCD per-K-step live slice =
// A-slice 256KB + B-slice 128KB -> L2-resident; A fetched 4x, B 1x chip-wide.
__global__ __launch_bounds__(256, 4) void k_gemm2(GemmP pa, GemmP pb) {
  __shared__ u16 smem[16384];  // 32 KB
  int id = blockIdx.y * 32 + blockIdx.x;  // 1024 blocks
  int xcd = id & 7, slot = id >> 3;       // slot in [0,128)
  const GemmP& p = (xcd & 1) ? pb : pa;
  int by = ((xcd >> 1) << 3) + (slot >> 4);  // 8 by per XCD-quadrant
  int bx = slot & 15;
  gemm_body(smem, p, bx << 7, by << 7);
}

// -------------------- small kernels --------------------

// g3: LSTM with H=1. One wave per batch row.
__global__ void k_g3(const u16* __restrict__ h2, const float* __restrict__ W,
                     const float* __restrict__ Uv, const float* __restrict__ bv,
                     float* __restrict__ c3, float* __restrict__ h3,
                     float* __restrict__ gen, int t) {
  int b = blockIdx.x * 4 + (threadIdx.x >> 6);
  int lane = threadIdx.x & 63;
  float a0 = 0.f, a1 = 0.f, a2 = 0.f, a3 = 0.f;
  for (int k = lane; k < H_; k += 64) {
    float hv = bf2f(h2[((size_t)b << 10) + k]);
    const f32x4 wv = *(const f32x4*)&W[k << 2];
    a0 += hv * wv.x; a1 += hv * wv.y; a2 += hv * wv.z; a3 += hv * wv.w;
  }
  for (int off = 32; off; off >>= 1) {
    a0 += __shfl_down(a0, off);
    a1 += __shfl_down(a1, off);
    a2 += __shfl_down(a2, off);
    a3 += __shfl_down(a3, off);
  }
  if (lane == 0) {
    float hp = h3[b];
    float zi = a0 + hp * Uv[0] + bv[0];
    float zf = a1 + hp * Uv[1] + bv[1];
    float zg = a2 + hp * Uv[2] + bv[2];
    float zo = a3 + hp * Uv[3] + bv[3];
    float cn = sigm(zf) * c3[b] + sigm(zi) * tanh_(zg);
    c3[b] = cn;
    float hn = sigm(zo) * tanh_(cn);
    h3[b] = hn;
    gen[b * T_ + t] = hn;
  }
}

// final dense: disc[b,t] = hd2[b,:] . do_W + do_b
__global__ void k_dense(const u16* __restrict__ hd2, const float* __restrict__ wv,
                        const float* __restrict__ bs, float* __restrict__ disc, int t) {
  int b = blockIdx.x * 4 + (threadIdx.x >> 6);
  int lane = threadIdx.x & 63;
  float a = 0.f;
  for (int k = lane; k < H_; k += 64)
    a += bf2f(hd2[((size_t)b << 10) + k]) * wv[k];
  for (int off = 32; off; off >>= 1) a += __shfl_down(a, off);
  if (lane == 0) disc[b * T_ + t] = a + bs[0];
}

// merged steady-state small kernel: blocks 0..511 -> g3[t+1], 512..1023 -> dense[t]
__global__ void k_small(const u16* __restrict__ h2s, const float* __restrict__ W,
                        const float* __restrict__ Uv, const float* __restrict__ bv,
                        float* __restrict__ c3, float* __restrict__ h3,
                        float* __restrict__ gen, int tg,
                        const u16* __restrict__ hd2s, const float* __restrict__ wv,
                        const float* __restrict__ bs, float* __restrict__ disc, int td) {
  int lane = threadIdx.x & 63;
  if (blockIdx.x < 512) {
    int b = blockIdx.x * 4 + (threadIdx.x >> 6);
    float a0 = 0.f, a1 = 0.f, a2 = 0.f, a3 = 0.f;
    for (int k = lane; k < H_; k += 64) {
      float hv = bf2f(h2s[((size_t)b << 10) + k]);
      const f32x4 wv4 = *(const f32x4*)&W[k << 2];
      a0 += hv * wv4.x; a1 += hv * wv4.y; a2 += hv * wv4.z; a3 += hv * wv4.w;
    }
    for (int off = 32; off; off >>= 1) {
      a0 += __shfl_down(a0, off);
      a1 += __shfl_down(a1, off);
      a2 += __shfl_down(a2, off);
      a3 += __shfl_down(a3, off);
    }
    if (lane == 0) {
      float hp = h3[b];
      float zi = a0 + hp * Uv[0] + bv[0];
      float zf = a1 + hp * Uv[1] + bv[1];
      float zg = a2 + hp * Uv[2] + bv[2];
      float zo = a3 + hp * Uv[3] + bv[3];
      float cn = sigm(zf) * c3[b] + sigm(zi) * tanh_(zg);
      c3[b] = cn;
      float hn = sigm(zo) * tanh_(cn);
      h3[b] = hn;
      gen[b * T_ + tg] = hn;
    }
  } else {
    int b = (blockIdx.x - 512) * 4 + (threadIdx.x >> 6);
    float a = 0.f;
    for (int k = lane; k < H_; k += 64)
      a += bf2f(hd2s[((size_t)b << 10) + k]) * wv[k];
    for (int off = 32; off; off >>= 1) a += __shfl_down(a, off);
    if (lane == 0) disc[b * T_ + td] = a + bs[0];
  }
}

// -------------------- launcher --------------------
// Software pipeline: generator chain at step t+1 runs concurrently (same launch)
// with discriminator chain at step t. 3 launches/step instead of 6.
//   J1(t) = {g1[t+1], d1[t]}   J2(t) = {g2[t+1], d2[t]}   S(t) = {g3[t+1], dense[t]}

extern "C" void kernel_launch(void* const* d_in, const int* in_sizes, int n_in,
                              void* d_out, int out_size, void* d_ws, size_t ws_size,
                              hipStream_t stream) {
  const float* x   = (const float*)d_in[0];
  const float* g1W = (const float*)d_in[1];
  const float* g1U = (const float*)d_in[2];
  const float* g1b = (const float*)d_in[3];
  const float* g2W = (const float*)d_in[4];
  const float* g2U = (const float*)d_in[5];
  const float* g2b = (const float*)d_in[6];
  const float* g3W = (const float*)d_in[7];
  const float* g3U = (const float*)d_in[8];
  const float* g3b = (const float*)d_in[9];
  const float* d1W = (const float*)d_in[10];
  const float* d1U = (const float*)d_in[11];
  const float* d1b = (const float*)d_in[12];
  const float* d2W = (const float*)d_in[13];
  const float* d2U = (const float*)d_in[14];
  const float* d2b = (const float*)d_in[15];
  const float* doW = (const float*)d_in[16];
  const float* dob = (const float*)d_in[17];

  char* ws = (char*)d_ws;
  u16* xT    = (u16*)(ws + 0);            // 16,777,216
  u16* BT1   = (u16*)(ws + 16777216);     //  8,912,896  [4096][1088]
  u16* BT2   = (u16*)(ws + 25690112);     // 16,777,216  [4096][2048]
  u16* BTd1  = (u16*)(ws + 42467328);     //  8,388,608  [4096][1024]
  u16* BTd2  = (u16*)(ws + 50855936);     // 16,777,216  [4096][2048]
  float* pb1  = (float*)(ws + 67633152);
  float* pb2  = (float*)(ws + 67649536);
  float* pbd1 = (float*)(ws + 67665920);
  float* pbd2 = (float*)(ws + 67682304);
  float* pd1W = (float*)(ws + 67698688);
  const size_t Z0 = 67715072;             // zeroed region start
  float* c1  = (float*)(ws + Z0);
  float* c2  = (float*)(ws + Z0 + 8388608);
  float* cd1 = (float*)(ws + Z0 + 16777216);
  float* cd2 = (float*)(ws + Z0 + 25165824);
  u16* h1[2]  = {(u16*)(ws + Z0 + 33554432), (u16*)(ws + Z0 + 37748736)};
  u16* h2[2]  = {(u16*)(ws + Z0 + 41943040), (u16*)(ws + Z0 + 46137344)};
  u16* hd1[2] = {(u16*)(ws + Z0 + 50331648), (u16*)(ws + Z0 + 54525952)};
  u16* hd2[2] = {(u16*)(ws + Z0 + 58720256), (u16*)(ws + Z0 + 62914560)};
  float* c3 = (float*)(ws + Z0 + 67108864);
  float* h3 = (float*)(ws + Z0 + 67117056);
  const size_t ZBYTES = 67125248;

  // setup (re-done every launch: ws is poisoned before each timed call)
  k_transpose_x<<<32768, 256, 0, stream>>>(x, xT);
  k_build_bt<<<dim3(5, 4096), 256, 0, stream>>>(g1U, g1W, BT1, 1024, 1088);
  k_build_bt<<<dim3(8, 4096), 256, 0, stream>>>(g2U, g2W, BT2, 1024, 2048);
  k_build_bt<<<dim3(4, 4096), 256, 0, stream>>>(d1U, nullptr, BTd1, 1024, 1024);
  k_build_bt<<<dim3(8, 4096), 256, 0, stream>>>(d2U, d2W, BTd2, 1024, 2048);
  k_build_bias<<<16, 256, 0, stream>>>(g1b, g2b, d1b, d2b, d1W, pb1, pb2, pbd1, pbd2, pd1W);
  (void)hipMemsetAsync(ws + Z0, 0, ZBYTES, stream);

  float* gen = (float*)d_out;
  float* disc = gen + (size_t)B_ * T_;
  dim3 blk(256);
  dim3 grid1(16, 32), grid2(32, 32);

  // ---- prolog: g-chain step 0 (t=0: rp=0, wp=1) ----
  {
    GemmP pg1 = {h1[0], H_, 16, xT, I_, 1, BT1, 1088,
                 pb1, nullptr, nullptr, 0, c1, h1[1]};
    k_gemm<<<grid1, blk, 0, stream>>>(pg1);
    GemmP pg2 = {h2[0], H_, 16, h1[1], H_, 16, BT2, 2048,
                 pb2, nullptr, nullptr, 0, c2, h2[1]};
    k_gemm<<<grid1, blk, 0, stream>>>(pg2);
    k_g3<<<512, blk, 0, stream>>>(h2[1], g3W, g3U, g3b, c3, h3, gen, 0);
  }

  // ---- steady state: t = 0..62 ----
  for (int t = 0; t < 63; ++t) {
    int rg = (t + 1) & 1, wg = rg ^ 1;  // g-chain step t+1 parity
    int rd = t & 1, wd = rd ^ 1;        // d-chain step t parity
    // J1: g1[t+1] || d1[t]
    GemmP pg1 = {h1[rg], H_, 16, xT + (size_t)(t + 1) * B_ * I_, I_, 1, BT1, 1088,
                 pb1, nullptr, nullptr, 0, c1, h1[wg]};
    GemmP pd1 = {hd1[rd], H_, 16, nullptr, 0, 0, BTd1, 1024,
                 pbd1, pd1W, gen + t, T_, cd1, hd1[wd]};
    k_gemm2<<<grid2, blk, 0, stream>>>(pg1, pd1);
    // J2: g2[t+1] || d2[t]
    GemmP pg2 = {h2[rg], H_, 16, h1[wg], H_, 16, BT2, 2048,
                 pb2, nullptr, nullptr, 0, c2, h2[wg]};
    GemmP pd2 = {hd2[rd], H_, 16, hd1[wd], H_, 16, BTd2, 2048,
                 pbd2, nullptr, nullptr, 0, cd2, hd2[wd]};
    k_gemm2<<<grid2, blk, 0, stream>>>(pg2, pd2);
    // S: g3[t+1] || dense[t]
    k_small<<<1024, blk, 0, stream>>>(h2[wg], g3W, g3U, g3b, c3, h3, gen, t + 1,
                                      hd2[wd], doW, dob, disc, t);
  }

  // ---- epilog: d-chain step 63 (rd=1, wd=0) ----
  {
    GemmP pd1 = {hd1[1], H_, 16, nullptr, 0, 0, BTd1, 1024,
                 pbd1, pd1W, gen + 63, T_, cd1, hd1[0]};
    k_gemm<<<grid1, blk, 0, stream>>>(pd1);
    GemmP pd2 = {hd2[1], H_, 16, hd1[0], H_, 16, BTd2, 2048,
                 pbd2, nullptr, nullptr, 0, cd2, hd2[0]};
    k_gemm<<<grid1, blk, 0, stream>>>(pd2);
    k_dense<<<512, blk, 0, stream>>>(hd2[0], doW, dob, disc, 63);
  }
  (void)in_sizes; (void)n_in; (void)out_size; (void)ws_size;
}

// Round 6
// 13783.508 us; speedup vs baseline: 3.1358x; 3.0166x over previous
//
#include <hip/hip_runtime.h>

typedef unsigned short u16;
typedef __attribute__((ext_vector_type(8))) short short8;
typedef __attribute__((ext_vector_type(4))) float f32x4;

#define B_ 2048
#define T_ 64
#define I_ 64
#define H_ 1024
#define G_ 4096

__device__ __forceinline__ float bf2f(u16 v) {
  union { float f; unsigned u; } x; x.u = ((unsigned)v) << 16; return x.f;
}
__device__ __forceinline__ u16 f2bf(float f) {
  union { float f; unsigned u; } x; x.f = f;
  unsigned r = x.u + 0x7fffu + ((x.u >> 16) & 1u);
  return (u16)(r >> 16);
}
__device__ __forceinline__ float sigm(float x) { return 1.0f / (1.0f + __expf(-x)); }
__device__ __forceinline__ float tanh_(float x) { return 1.0f - 2.0f / (__expf(2.0f * x) + 1.0f); }

// -------------------- setup kernels --------------------

// x [B,T,I] fp32 -> xT [T,B,I] bf16
__global__ void k_transpose_x(const float* __restrict__ x, u16* __restrict__ xT) {
  int idx = blockIdx.x * 256 + threadIdx.x;  // over B*T*I = 8388608
  if (idx >= B_ * T_ * I_) return;
  int i = idx & 63;
  int t = (idx >> 6) & 63;
  int b = idx >> 12;
  xT[((size_t)t * B_ + b) * I_ + i] = f2bf(x[idx]);
}

// Build BT [4096][K] bf16: rows are permuted output cols n' = 4*unit + gate,
// k<K0 from U (recurrent), k>=K0 from W (input). Orig col j = gate*1024 + unit.
__global__ void k_build_bt(const float* __restrict__ U, const float* __restrict__ W,
                           u16* __restrict__ BT, int K0, int K) {
  int n = blockIdx.y;
  int k = blockIdx.x * 256 + threadIdx.x;
  if (k >= K) return;
  int j = (n & 3) * 1024 + (n >> 2);
  float v = (k < K0) ? U[(size_t)k * G_ + j] : W[(size_t)(k - K0) * G_ + j];
  BT[(size_t)n * K + k] = f2bf(v);
}

__global__ void k_build_bias(const float* __restrict__ b1, const float* __restrict__ b2,
                             const float* __restrict__ bd1, const float* __restrict__ bd2,
                             const float* __restrict__ d1W,
                             float* __restrict__ p1, float* __restrict__ p2,
                             float* __restrict__ pd1, float* __restrict__ pd2,
                             float* __restrict__ pd1W) {
  int n = blockIdx.x * 256 + threadIdx.x;
  if (n >= G_) return;
  int j = (n & 3) * 1024 + (n >> 2);
  p1[n] = b1[j]; p2[n] = b2[j]; pd1[n] = bd1[j]; pd2[n] = bd2[j];
  pd1W[n] = d1W[j];
}

// -------------------- fused GEMM + LSTM cell --------------------

struct GemmP {
  const u16* A0; int lda0, kt0;
  const u16* A1; int lda1, kt1;
  const u16* BT; int ldb;
  const float* biasp;
  const float* evec;
  const float* escal; int estride;
  float* cst; u16* hout;
};

// z[m, n'] = sum_k A[m,k] * BT[n',k]  (A = [A0 seg | A1 seg] along K)
// then per (m, unit): i,f,g,o = z cols 4u..4u+3 (+bias, + optional gen*d1_W),
// c = f*c + i*g; h = o*tanh(c) -> hout bf16.
//
// Staging is REGISTER-staged (no global_load_lds: on gfx950 the LDS-DMA path
// shows up as ~2 B/B of TCC-EA WRITE traffic -> fabric-bound at 6.2 TB/s).
// Linear coalesced global loads -> XOR-swizzled ds_write_b128 (read side and
// LDS layout unchanged: LDS chunk ch of row rs holds global chunk ch^(rs&7)).
// 1-deep prefetch: loads for kt+1 issued before the compute phase of kt; the
// k-loop barriers wait lgkmcnt only (no vmcnt drain) so loads stay in flight.
__device__ __forceinline__ void gemm_body(u16* smem, const GemmP& p, int m0, int n0) {
  const int tid = threadIdx.x;
  const int lane = tid & 63;
  const int w = tid >> 6;
  const int KT = p.kt0 + p.kt1;

  // thread covers LDS row rs = s*32 + tid/8, chunk c_ = tid&7 (linear global)
  const int r_ = tid >> 3, c_ = tid & 7;
  const u16* pA0[4]; const u16* pA1[4]; const u16* pB[4];
  int wpos[4];  // swizzled LDS u16-offset for (rs, c_^(rs&7))
#pragma unroll
  for (int s = 0; s < 4; ++s) {
    int rs = (s << 5) + r_;
    pA0[s] = p.A0 + (size_t)(m0 + rs) * p.lda0 + (c_ << 3);
    pA1[s] = p.A1 ? (p.A1 + (size_t)(m0 + rs) * p.lda1 + (c_ << 3)) : pA0[s];
    pB[s] = p.BT + (size_t)(n0 + rs) * p.ldb + (c_ << 3);
    wpos[s] = (rs << 6) + ((c_ ^ (rs & 7)) << 3);
  }

  f32x4 acc[4][4];
#pragma unroll
  for (int i = 0; i < 4; ++i)
#pragma unroll
    for (int j = 0; j < 4; ++j) acc[i][j] = (f32x4){0.f, 0.f, 0.f, 0.f};

  const int wm = (w >> 1) << 6, wn = (w & 1) << 6;
  const int q = lane >> 4, l15 = lane & 15, l7 = lane & 7;
  int aoffr[4], boffr[4];
#pragma unroll
  for (int i = 0; i < 4; ++i) {
    aoffr[i] = (wm + (i << 4) + l15) << 6;
    boffr[i] = 8192 + ((wn + (i << 4) + l15) << 6);
  }

  short8 ra[4], rb[4];
  // prologue: load tile 0 into registers
  {
    bool s0 = (0 < p.kt0);
#pragma unroll
    for (int s = 0; s < 4; ++s) {
      const u16* ga = s0 ? pA0[s] : pA1[s];
      ra[s] = *(const short8*)ga;
      rb[s] = *(const short8*)pB[s];
    }
  }

  for (int kt = 0; kt < KT; ++kt) {
    // prev iteration's ds_reads complete -> LDS safe to overwrite.
    asm volatile("s_waitcnt lgkmcnt(0)" ::: "memory");
    __builtin_amdgcn_s_barrier();
    // write current tile (vmcnt wait for ra/rb inserted by compiler via data dep)
#pragma unroll
    for (int s = 0; s < 4; ++s) {
      *(short8*)&smem[wpos[s]] = ra[s];
      *(short8*)&smem[8192 + wpos[s]] = rb[s];
    }
    // prefetch next tile (stays in flight across the barrier below)
    if (kt + 1 < KT) {
      bool s0 = (kt + 1 < p.kt0);
#pragma unroll
      for (int s = 0; s < 4; ++s) {
        const u16* ga = s0 ? (pA0[s] + (size_t)(kt + 1) * 64)
                           : (pA1[s] + (size_t)(kt + 1 - p.kt0) * 64);
        ra[s] = *(const short8*)ga;
        rb[s] = *(const short8*)(pB[s] + (size_t)(kt + 1) * 64);
      }
    }
    // my ds_writes visible to all waves
    asm volatile("s_waitcnt lgkmcnt(0)" ::: "memory");
    __builtin_amdgcn_s_barrier();
#pragma unroll
    for (int ks = 0; ks < 2; ++ks) {
      const int sw = ((((ks << 2) + q) ^ l7) << 3);
      short8 af[4], bfr[4];
#pragma unroll
      for (int i = 0; i < 4; ++i) {
        af[i] = *(const short8*)&smem[aoffr[i] + sw];
        bfr[i] = *(const short8*)&smem[boffr[i] + sw];
      }
#pragma unroll
      for (int i = 0; i < 4; ++i)
#pragma unroll
        for (int j = 0; j < 4; ++j)
          acc[i][j] = __builtin_amdgcn_mfma_f32_16x16x32_bf16(af[i], bfr[j], acc[i][j], 0, 0, 0);
    }
  }

  // ---- fused LSTM-cell epilogue (LDS reshuffle: C-layout -> per-lane 4 gates) ----
  __syncthreads();
  float* ep = (float*)smem + w * 1280;  // per-wave [64][20] fp32 region
  const int ul = lane & 3, ml = lane >> 2;
  const int ubase = (n0 >> 2) + (wn >> 2);
#pragma unroll 1
  for (int tj = 0; tj < 4; ++tj) {
#pragma unroll
    for (int ti = 0; ti < 4; ++ti)
#pragma unroll
      for (int v = 0; v < 4; ++v)
        ep[((ti << 4) + (q << 2) + v) * 20 + l15] = acc[ti][tj][v];
    __syncthreads();
#pragma unroll
    for (int pp = 0; pp < 4; ++pp) {
      int row = ml + (pp << 4);
      f32x4 z = *(const f32x4*)&ep[row * 20 + (ul << 2)];
      int gm = m0 + wm + row;
      int gu = ubase + (tj << 2) + ul;
      const f32x4 bb = *(const f32x4*)&p.biasp[gu << 2];
      z.x += bb.x; z.y += bb.y; z.z += bb.z; z.w += bb.w;
      if (p.evec) {  // d1: + gen[m] * d1_W[n']  (K=1 input folded here, fp32)
        float gs = p.escal[(size_t)gm * p.estride];
        const f32x4 ev = *(const f32x4*)&p.evec[gu << 2];
        z.x += gs * ev.x; z.y += gs * ev.y; z.z += gs * ev.z; z.w += gs * ev.w;
      }
      float ig = sigm(z.x), fg = sigm(z.y), gg = tanh_(z.z), og = sigm(z.w);
      size_t ci = ((size_t)gm << 10) + gu;
      float cn = fg * p.cst[ci] + ig * gg;
      p.cst[ci] = cn;
      p.hout[ci] = f2bf(og * tanh_(cn));
    }
    __syncthreads();
  }
}

// single-problem wrapper (pipeline prolog/epilog), 512 blocks.
// XCD-local mapping: HW round-robins linear id across the 8 XCDs (id&7 = xcd).
// Each XCD gets 4 contiguous by (n-rows) x all 16 bx -> per-K-step live slice
// (A 256KB + B 64KB) is L2-resident; B fetched once chip-wide.
__global__ __launch_bounds__(256, 3) void k_gemm(GemmP p) {
  __shared__ u16 smem[16384];  // 32 KB
  int id = blockIdx.y * 16 + blockIdx.x;  // 512 blocks
  int xcd = id & 7, slot = id >> 3;       // slot in [0,64)
  int by = (xcd << 2) + (slot >> 4);      // 4 by per XCD
  int bx = slot & 15;
  gemm_body(smem, p, bx << 7, by << 7);
}

// paired wrapper: two INDEPENDENT problems. XCD parity selects the problem
// (4 XCDs each) so one XCD touches ONE problem's A/B only; within the XCD,
// a contiguous 8-wide by chunk x all 16 bx. Per-XCD per-K-step live slice =
// A-slice 256KB + B-slice 128KB -> L2-resident; A fetched 4x, B 1x chip-wide.
__global__ __launch_bounds__(256, 3) void k_gemm2(GemmP pa, GemmP pb) {
  __shared__ u16 smem[16384];  // 32 KB
  int id = blockIdx.y * 32 + blockIdx.x;  // 1024 blocks
  int xcd = id & 7, slot = id >> 3;       // slot in [0,128)
  const GemmP& p = (xcd & 1) ? pb : pa;
  int by = ((xcd >> 1) << 3) + (slot >> 4);  // 8 by per XCD-quadrant
  int bx = slot & 15;
  gemm_body(smem, p, bx << 7, by << 7);
}

// -------------------- small kernels --------------------

// g3: LSTM with H=1. One wave per batch row.
__global__ void k_g3(const u16* __restrict__ h2, const float* __restrict__ W,
                     const float* __restrict__ Uv, const float* __restrict__ bv,
                     float* __restrict__ c3, float* __restrict__ h3,
                     float* __restrict__ gen, int t) {
  int b = blockIdx.x * 4 + (threadIdx.x >> 6);
  int lane = threadIdx.x & 63;
  float a0 = 0.f, a1 = 0.f, a2 = 0.f, a3 = 0.f;
  for (int k = lane; k < H_; k += 64) {
    float hv = bf2f(h2[((size_t)b << 10) + k]);
    const f32x4 wv = *(const f32x4*)&W[k << 2];
    a0 += hv * wv.x; a1 += hv * wv.y; a2 += hv * wv.z; a3 += hv * wv.w;
  }
  for (int off = 32; off; off >>= 1) {
    a0 += __shfl_down(a0, off);
    a1 += __shfl_down(a1, off);
    a2 += __shfl_down(a2, off);
    a3 += __shfl_down(a3, off);
  }
  if (lane == 0) {
    float hp = h3[b];
    float zi = a0 + hp * Uv[0] + bv[0];
    float zf = a1 + hp * Uv[1] + bv[1];
    float zg = a2 + hp * Uv[2] + bv[2];
    float zo = a3 + hp * Uv[3] + bv[3];
    float cn = sigm(zf) * c3[b] + sigm(zi) * tanh_(zg);
    c3[b] = cn;
    float hn = sigm(zo) * tanh_(cn);
    h3[b] = hn;
    gen[b * T_ + t] = hn;
  }
}

// final dense: disc[b,t] = hd2[b,:] . do_W + do_b
__global__ void k_dense(const u16* __restrict__ hd2, const float* __restrict__ wv,
                        const float* __restrict__ bs, float* __restrict__ disc, int t) {
  int b = blockIdx.x * 4 + (threadIdx.x >> 6);
  int lane = threadIdx.x & 63;
  float a = 0.f;
  for (int k = lane; k < H_; k += 64)
    a += bf2f(hd2[((size_t)b << 10) + k]) * wv[k];
  for (int off = 32; off; off >>= 1) a += __shfl_down(a, off);
  if (lane == 0) disc[b * T_ + t] = a + bs[0];
}

// merged steady-state small kernel: blocks 0..511 -> g3[t+1], 512..1023 -> dense[t]
__global__ void k_small(const u16* __restrict__ h2s, const float* __restrict__ W,
                        const float* __restrict__ Uv, const float* __restrict__ bv,
                        float* __restrict__ c3, float* __restrict__ h3,
                        float* __restrict__ gen, int tg,
                        const u16* __restrict__ hd2s, const float* __restrict__ wv,
                        const float* __restrict__ bs, float* __restrict__ disc, int td) {
  int lane = threadIdx.x & 63;
  if (blockIdx.x < 512) {
    int b = blockIdx.x * 4 + (threadIdx.x >> 6);
    float a0 = 0.f, a1 = 0.f, a2 = 0.f, a3 = 0.f;
    for (int k = lane; k < H_; k += 64) {
      float hv = bf2f(h2s[((size_t)b << 10) + k]);
      const f32x4 wv4 = *(const f32x4*)&W[k << 2];
      a0 += hv * wv4.x; a1 += hv * wv4.y; a2 += hv * wv4.z; a3 += hv * wv4.w;
    }
    for (int off = 32; off; off >>= 1) {
      a0 += __shfl_down(a0, off);
      a1 += __shfl_down(a1, off);
      a2 += __shfl_down(a2, off);
      a3 += __shfl_down(a3, off);
    }
    if (lane == 0) {
      float hp = h3[b];
      float zi = a0 + hp * Uv[0] + bv[0];
      float zf = a1 + hp * Uv[1] + bv[1];
      float zg = a2 + hp * Uv[2] + bv[2];
      float zo = a3 + hp * Uv[3] + bv[3];
      float cn = sigm(zf) * c3[b] + sigm(zi) * tanh_(zg);
      c3[b] = cn;
      float hn = sigm(zo) * tanh_(cn);
      h3[b] = hn;
      gen[b * T_ + tg] = hn;
    }
  } else {
    int b = (blockIdx.x - 512) * 4 + (threadIdx.x >> 6);
    float a = 0.f;
    for (int k = lane; k < H_; k += 64)
      a += bf2f(hd2s[((size_t)b << 10) + k]) * wv[k];
    for (int off = 32; off; off >>= 1) a += __shfl_down(a, off);
    if (lane == 0) disc[b * T_ + td] = a + bs[0];
  }
}

// -------------------- launcher --------------------
// Software pipeline: generator chain at step t+1 runs concurrently (same launch)
// with discriminator chain at step t. 3 launches/step instead of 6.
//   J1(t) = {g1[t+1], d1[t]}   J2(t) = {g2[t+1], d2[t]}   S(t) = {g3[t+1], dense[t]}

extern "C" void kernel_launch(void* const* d_in, const int* in_sizes, int n_in,
                              void* d_out, int out_size, void* d_ws, size_t ws_size,
                              hipStream_t stream) {
  const float* x   = (const float*)d_in[0];
  const float* g1W = (const float*)d_in[1];
  const float* g1U = (const float*)d_in[2];
  const float* g1b = (const float*)d_in[3];
  const float* g2W = (const float*)d_in[4];
  const float* g2U = (const float*)d_in[5];
  const float* g2b = (const float*)d_in[6];
  const float* g3W = (const float*)d_in[7];
  const float* g3U = (const float*)d_in[8];
  const float* g3b = (const float*)d_in[9];
  const float* d1W = (const float*)d_in[10];
  const float* d1U = (const float*)d_in[11];
  const float* d1b = (const float*)d_in[12];
  const float* d2W = (const float*)d_in[13];
  const float* d2U = (const float*)d_in[14];
  const float* d2b = (const float*)d_in[15];
  const float* doW = (const float*)d_in[16];
  const float* dob = (const float*)d_in[17];

  char* ws = (char*)d_ws;
  u16* xT    = (u16*)(ws + 0);            // 16,777,216
  u16* BT1   = (u16*)(ws + 16777216);     //  8,912,896  [4096][1088]
  u16* BT2   = (u16*)(ws + 25690112);     // 16,777,216  [4096][2048]
  u16* BTd1  = (u16*)(ws + 42467328);     //  8,388,608  [4096][1024]
  u16* BTd2  = (u16*)(ws + 50855936);     // 16,777,216  [4096][2048]
  float* pb1  = (float*)(ws + 67633152);
  float* pb2  = (float*)(ws + 67649536);
  float* pbd1 = (float*)(ws + 67665920);
  float* pbd2 = (float*)(ws + 67682304);
  float* pd1W = (float*)(ws + 67698688);
  const size_t Z0 = 67715072;             // zeroed region start
  float* c1  = (float*)(ws + Z0);
  float* c2  = (float*)(ws + Z0 + 8388608);
  float* cd1 = (float*)(ws + Z0 + 16777216);
  float* cd2 = (float*)(ws + Z0 + 25165824);
  u16* h1[2]  = {(u16*)(ws + Z0 + 33554432), (u16*)(ws + Z0 + 37748736)};
  u16* h2[2]  = {(u16*)(ws + Z0 + 41943040), (u16*)(ws + Z0 + 46137344)};
  u16* hd1[2] = {(u16*)(ws + Z0 + 50331648), (u16*)(ws + Z0 + 54525952)};
  u16* hd2[2] = {(u16*)(ws + Z0 + 58720256), (u16*)(ws + Z0 + 62914560)};
  float* c3 = (float*)(ws + Z0 + 67108864);
  float* h3 = (float*)(ws + Z0 + 67117056);
  const size_t ZBYTES = 67125248;

  // setup (re-done every launch: ws is poisoned before each timed call)
  k_transpose_x<<<32768, 256, 0, stream>>>(x, xT);
  k_build_bt<<<dim3(5, 4096), 256, 0, stream>>>(g1U, g1W, BT1, 1024, 1088);
  k_build_bt<<<dim3(8, 4096), 256, 0, stream>>>(g2U, g2W, BT2, 1024, 2048);
  k_build_bt<<<dim3(4, 4096), 256, 0, stream>>>(d1U, nullptr, BTd1, 1024, 1024);
  k_build_bt<<<dim3(8, 4096), 256, 0, stream>>>(d2U, d2W, BTd2, 1024, 2048);
  k_build_bias<<<16, 256, 0, stream>>>(g1b, g2b, d1b, d2b, d1W, pb1, pb2, pbd1, pbd2, pd1W);
  (void)hipMemsetAsync(ws + Z0, 0, ZBYTES, stream);

  float* gen = (float*)d_out;
  float* disc = gen + (size_t)B_ * T_;
  dim3 blk(256);
  dim3 grid1(16, 32), grid2(32, 32);

  // ---- prolog: g-chain step 0 (t=0: rp=0, wp=1) ----
  {
    GemmP pg1 = {h1[0], H_, 16, xT, I_, 1, BT1, 1088,
                 pb1, nullptr, nullptr, 0, c1, h1[1]};
    k_gemm<<<grid1, blk, 0, stream>>>(pg1);
    GemmP pg2 = {h2[0], H_, 16, h1[1], H_, 16, BT2, 2048,
                 pb2, nullptr, nullptr, 0, c2, h2[1]};
    k_gemm<<<grid1, blk, 0, stream>>>(pg2);
    k_g3<<<512, blk, 0, stream>>>(h2[1], g3W, g3U, g3b, c3, h3, gen, 0);
  }

  // ---- steady state: t = 0..62 ----
  for (int t = 0; t < 63; ++t) {
    int rg = (t + 1) & 1, wg = rg ^ 1;  // g-chain step t+1 parity
    int rd = t & 1, wd = rd ^ 1;        // d-chain step t parity
    // J1: g1[t+1] || d1[t]
    GemmP pg1 = {h1[rg], H_, 16, xT + (size_t)(t + 1) * B_ * I_, I_, 1, BT1, 1088,
                 pb1, nullptr, nullptr, 0, c1, h1[wg]};
    GemmP pd1 = {hd1[rd], H_, 16, nullptr, 0, 0, BTd1, 1024,
                 pbd1, pd1W, gen + t, T_, cd1, hd1[wd]};
    k_gemm2<<<grid2, blk, 0, stream>>>(pg1, pd1);
    // J2: g2[t+1] || d2[t]
    GemmP pg2 = {h2[rg], H_, 16, h1[wg], H_, 16, BT2, 2048,
                 pb2, nullptr, nullptr, 0, c2, h2[wg]};
    GemmP pd2 = {hd2[rd], H_, 16, hd1[wd], H_, 16, BTd2, 2048,
                 pbd2, nullptr, nullptr, 0, cd2, hd2[wd]};
    k_gemm2<<<grid2, blk, 0, stream>>>(pg2, pd2);
    // S: g3[t+1] || dense[t]
    k_small<<<1024, blk, 0, stream>>>(h2[wg], g3W, g3U, g3b, c3, h3, gen, t + 1,
                                      hd2[wd], doW, dob, disc, t);
  }

  // ---- epilog: d-chain step 63 (rd=1, wd=0) ----
  {
    GemmP pd1 = {hd1[1], H_, 16, nullptr, 0, 0, BTd1, 1024,
                 pbd1, pd1W, gen + 63, T_, cd1, hd1[0]};
    k_gemm<<<grid1, blk, 0, stream>>>(pd1);
    GemmP pd2 = {hd2[1], H_, 16, hd1[0], H_, 16, BTd2, 2048,
                 pbd2, nullptr, nullptr, 0, cd2, hd2[0]};
    k_gemm<<<grid1, blk, 0, stream>>>(pd2);
    k_dense<<<512, blk, 0, stream>>>(hd2[0], doW, dob, disc, 63);
  }
  (void)in_sizes; (void)n_in; (void)out_size; (void)ws_size;
}

// Round 7
// 13629.088 us; speedup vs baseline: 3.1713x; 1.0113x over previous
//
#include <hip/hip_runtime.h>

typedef unsigned short u16;
typedef __attribute__((ext_vector_type(8))) short short8;
typedef __attribute__((ext_vector_type(4))) float f32x4;

#define B_ 2048
#define T_ 64
#define I_ 64
#define H_ 1024
#define G_ 4096

__device__ __forceinline__ float bf2f(u16 v) {
  union { float f; unsigned u; } x; x.u = ((unsigned)v) << 16; return x.f;
}
__device__ __forceinline__ u16 f2bf(float f) {
  union { float f; unsigned u; } x; x.f = f;
  unsigned r = x.u + 0x7fffu + ((x.u >> 16) & 1u);
  return (u16)(r >> 16);
}
__device__ __forceinline__ float sigm(float x) { return 1.0f / (1.0f + __expf(-x)); }
__device__ __forceinline__ float tanh_(float x) { return 1.0f - 2.0f / (__expf(2.0f * x) + 1.0f); }

// -------------------- setup kernels --------------------

// x [B,T,I] fp32 -> xT [T,B,I] bf16
__global__ void k_transpose_x(const float* __restrict__ x, u16* __restrict__ xT) {
  int idx = blockIdx.x * 256 + threadIdx.x;  // over B*T*I = 8388608
  if (idx >= B_ * T_ * I_) return;
  int i = idx & 63;
  int t = (idx >> 6) & 63;
  int b = idx >> 12;
  xT[((size_t)t * B_ + b) * I_ + i] = f2bf(x[idx]);
}

// Build BT [4096][K] bf16: rows are permuted output cols n' = 4*unit + gate,
// k<K0 from U (recurrent), k>=K0 from W (input). Orig col j = gate*1024 + unit.
__global__ void k_build_bt(const float* __restrict__ U, const float* __restrict__ W,
                           u16* __restrict__ BT, int K0, int K) {
  int n = blockIdx.y;
  int k = blockIdx.x * 256 + threadIdx.x;
  if (k >= K) return;
  int j = (n & 3) * 1024 + (n >> 2);
  float v = (k < K0) ? U[(size_t)k * G_ + j] : W[(size_t)(k - K0) * G_ + j];
  BT[(size_t)n * K + k] = f2bf(v);
}

__global__ void k_build_bias(const float* __restrict__ b1, const float* __restrict__ b2,
                             const float* __restrict__ bd1, const float* __restrict__ bd2,
                             const float* __restrict__ d1W,
                             float* __restrict__ p1, float* __restrict__ p2,
                             float* __restrict__ pd1, float* __restrict__ pd2,
                             float* __restrict__ pd1W) {
  int n = blockIdx.x * 256 + threadIdx.x;
  if (n >= G_) return;
  int j = (n & 3) * 1024 + (n >> 2);
  p1[n] = b1[j]; p2[n] = b2[j]; pd1[n] = bd1[j]; pd2[n] = bd2[j];
  pd1W[n] = d1W[j];
}

// -------------------- fused GEMM + LSTM cell --------------------

struct GemmP {
  const u16* A0; int lda0, kt0;
  const u16* A1; int lda1, kt1;
  const u16* BT; int ldb;
  const float* biasp;
  const float* evec;
  const float* escal; int estride;
  float* cst; u16* hout;
};

// Register-staged (NO global_load_lds: on gfx950 the LDS-DMA path generates
// ~2 B/B of TCC-EA WRITE traffic -> fabric-bound; round 6 proved removal = 3x).
// This round: LDS DOUBLE-BUFFER (2 x 32KB) -> ONE barrier + ONE lgkm drain per
// K-tile; two named register staging sets (static indexing only), loads issued
// ~1.5 phases before their ds_write consumes them; ds_writes to buf^1 overlap
// ds_read+MFMA on buf. No vmcnt(0) drain anywhere in the loop.

#define LOADT(kt_, ta, tb) do {                                              \
    int kk_ = (kt_);                                                         \
    bool s0_ = (kk_ < p.kt0);                                                \
    size_t offA_ = s0_ ? (size_t)kk_ * 64 : (size_t)(kk_ - p.kt0) * 64;      \
    _Pragma("unroll")                                                        \
    for (int s = 0; s < 4; ++s) {                                            \
      ta[s] = *(const short8*)((s0_ ? pA0[s] : pA1[s]) + offA_);             \
      tb[s] = *(const short8*)(pB[s] + (size_t)kk_ * 64);                    \
    }                                                                        \
  } while (0)

#define WRITET(ta, tb, SOFF) do {                                            \
    _Pragma("unroll")                                                        \
    for (int s = 0; s < 4; ++s) {                                            \
      *(short8*)&smem[(SOFF) + wpos[s]] = ta[s];                             \
      *(short8*)&smem[(SOFF) + 8192 + wpos[s]] = tb[s];                      \
    }                                                                        \
  } while (0)

#define COMPUTET(SOFF) do {                                                  \
    __builtin_amdgcn_s_setprio(1);                                           \
    _Pragma("unroll")                                                        \
    for (int ks = 0; ks < 2; ++ks) {                                         \
      const int sw = ((((ks << 2) + q) ^ l7) << 3);                          \
      short8 af[4], bfv[4];                                                  \
      _Pragma("unroll")                                                      \
      for (int i = 0; i < 4; ++i) {                                          \
        af[i] = *(const short8*)&smem[(SOFF) + aoffr[i] + sw];               \
        bfv[i] = *(const short8*)&smem[(SOFF) + boffr[i] + sw];              \
      }                                                                      \
      _Pragma("unroll")                                                      \
      for (int i = 0; i < 4; ++i)                                            \
        _Pragma("unroll")                                                    \
        for (int j = 0; j < 4; ++j)                                          \
          acc[i][j] = __builtin_amdgcn_mfma_f32_16x16x32_bf16(af[i], bfv[j], acc[i][j], 0, 0, 0); \
    }                                                                        \
    __builtin_amdgcn_s_setprio(0);                                           \
  } while (0)

#define KBAR() do {                                                          \
    asm volatile("s_waitcnt lgkmcnt(0)" ::: "memory");                       \
    __builtin_amdgcn_s_barrier();                                            \
  } while (0)

__device__ __forceinline__ void gemm_body(u16* smem, const GemmP& p, int m0, int n0) {
  const int tid = threadIdx.x;
  const int lane = tid & 63;
  const int w = tid >> 6;
  const int KT = p.kt0 + p.kt1;

  // thread covers LDS row rs = s*32 + tid/8, chunk c_ = tid&7 (linear global);
  // LDS chunk ch of row rs holds global chunk ch^(rs&7) (XOR swizzle on write)
  const int r_ = tid >> 3, c_ = tid & 7;
  const u16* pA0[4]; const u16* pA1[4]; const u16* pB[4];
  int wpos[4];
#pragma unroll
  for (int s = 0; s < 4; ++s) {
    int rs = (s << 5) + r_;
    pA0[s] = p.A0 + (size_t)(m0 + rs) * p.lda0 + (c_ << 3);
    pA1[s] = p.A1 ? (p.A1 + (size_t)(m0 + rs) * p.lda1 + (c_ << 3)) : pA0[s];
    pB[s] = p.BT + (size_t)(n0 + rs) * p.ldb + (c_ << 3);
    wpos[s] = (rs << 6) + ((c_ ^ (rs & 7)) << 3);
  }

  f32x4 acc[4][4];
#pragma unroll
  for (int i = 0; i < 4; ++i)
#pragma unroll
    for (int j = 0; j < 4; ++j) acc[i][j] = (f32x4){0.f, 0.f, 0.f, 0.f};

  const int wm = (w >> 1) << 6, wn = (w & 1) << 6;
  const int q = lane >> 4, l15 = lane & 15, l7 = lane & 7;
  int aoffr[4], boffr[4];
#pragma unroll
  for (int i = 0; i < 4; ++i) {
    aoffr[i] = (wm + (i << 4) + l15) << 6;
    boffr[i] = 8192 + ((wn + (i << 4) + l15) << 6);
  }

  short8 sa0[4], sb0[4], sa1[4], sb1[4];

  // prologue: tiles 0 and 1 into the two reg sets; tile 0 -> buf0
  LOADT(0, sa0, sb0);
  LOADT(1, sa1, sb1);
  WRITET(sa0, sb0, 0);
  KBAR();

  for (int kt = 0; kt < KT; kt += 2) {
    // even phase: compute buf0 (tile kt); write tile kt+1 -> buf1; reload sa0 <- tile kt+2
    if (kt + 2 < KT) LOADT(kt + 2, sa0, sb0);
    if (kt + 1 < KT) WRITET(sa1, sb1, 16384);
    COMPUTET(0);
    KBAR();
    if (kt + 1 >= KT) break;
    // odd phase: compute buf1 (tile kt+1); write tile kt+2 -> buf0; reload sa1 <- tile kt+3
    if (kt + 3 < KT) LOADT(kt + 3, sa1, sb1);
    if (kt + 2 < KT) WRITET(sa0, sb0, 0);
    COMPUTET(16384);
    KBAR();
  }

  // ---- fused LSTM-cell epilogue (LDS reshuffle: C-layout -> per-lane 4 gates) ----
  __syncthreads();
  float* ep = (float*)smem + w * 1280;  // per-wave [64][20] fp32 region
  const int ul = lane & 3, ml = lane >> 2;
  const int ubase = (n0 >> 2) + (wn >> 2);
#pragma unroll 1
  for (int tj = 0; tj < 4; ++tj) {
#pragma unroll
    for (int ti = 0; ti < 4; ++ti)
#pragma unroll
      for (int v = 0; v < 4; ++v)
        ep[((ti << 4) + (q << 2) + v) * 20 + l15] = acc[ti][tj][v];
    __syncthreads();
#pragma unroll
    for (int pp = 0; pp < 4; ++pp) {
      int row = ml + (pp << 4);
      f32x4 z = *(const f32x4*)&ep[row * 20 + (ul << 2)];
      int gm = m0 + wm + row;
      int gu = ubase + (tj << 2) + ul;
      const f32x4 bb = *(const f32x4*)&p.biasp[gu << 2];
      z.x += bb.x; z.y += bb.y; z.z += bb.z; z.w += bb.w;
      if (p.evec) {  // d1: + gen[m] * d1_W[n']  (K=1 input folded here, fp32)
        float gs = p.escal[(size_t)gm * p.estride];
        const f32x4 ev = *(const f32x4*)&p.evec[gu << 2];
        z.x += gs * ev.x; z.y += gs * ev.y; z.z += gs * ev.z; z.w += gs * ev.w;
      }
      float ig = sigm(z.x), fg = sigm(z.y), gg = tanh_(z.z), og = sigm(z.w);
      size_t ci = ((size_t)gm << 10) + gu;
      float cn = fg * p.cst[ci] + ig * gg;
      p.cst[ci] = cn;
      p.hout[ci] = f2bf(og * tanh_(cn));
    }
    __syncthreads();
  }
}

// single-problem wrapper (pipeline prolog/epilog), 512 blocks.
// XCD-local mapping: HW round-robins linear id across the 8 XCDs (id&7 = xcd).
// Each XCD gets 4 contiguous by (n-rows) x all 16 bx -> per-K-step live slice
// is L2-resident; B fetched once chip-wide.
__global__ __launch_bounds__(256, 2) void k_gemm(GemmP p) {
  __shared__ u16 smem[32768];  // 64 KB: double-buffered {A 16K | B 16K} x2
  int id = blockIdx.y * 16 + blockIdx.x;  // 512 blocks
  int xcd = id & 7, slot = id >> 3;       // slot in [0,64)
  int by = (xcd << 2) + (slot >> 4);      // 4 by per XCD
  int bx = slot & 15;
  gemm_body(smem, p, bx << 7, by << 7);
}

// paired wrapper: two INDEPENDENT problems. XCD parity selects the problem
// (4 XCDs each) so one XCD touches ONE problem's A/B only; within the XCD,
// a contiguous 8-wide by chunk x all 16 bx.
__global__ __launch_bounds__(256, 2) void k_gemm2(GemmP pa, GemmP pb) {
  __shared__ u16 smem[32768];  // 64 KB
  int id = blockIdx.y * 32 + blockIdx.x;  // 1024 blocks
  int xcd = id & 7, slot = id >> 3;       // slot in [0,128)
  const GemmP& p = (xcd & 1) ? pb : pa;
  int by = ((xcd >> 1) << 3) + (slot >> 4);  // 8 by per XCD-quadrant
  int bx = slot & 15;
  gemm_body(smem, p, bx << 7, by << 7);
}

// -------------------- small kernels --------------------

// g3: LSTM with H=1. One wave per batch row.
__global__ void k_g3(const u16* __restrict__ h2, const float* __restrict__ W,
                     const float* __restrict__ Uv, const float* __restrict__ bv,
                     float* __restrict__ c3, float* __restrict__ h3,
                     float* __restrict__ gen, int t) {
  int b = blockIdx.x * 4 + (threadIdx.x >> 6);
  int lane = threadIdx.x & 63;
  float a0 = 0.f, a1 = 0.f, a2 = 0.f, a3 = 0.f;
  for (int k = lane; k < H_; k += 64) {
    float hv = bf2f(h2[((size_t)b << 10) + k]);
    const f32x4 wv = *(const f32x4*)&W[k << 2];
    a0 += hv * wv.x; a1 += hv * wv.y; a2 += hv * wv.z; a3 += hv * wv.w;
  }
  for (int off = 32; off; off >>= 1) {
    a0 += __shfl_down(a0, off);
    a1 += __shfl_down(a1, off);
    a2 += __shfl_down(a2, off);
    a3 += __shfl_down(a3, off);
  }
  if (lane == 0) {
    float hp = h3[b];
    float zi = a0 + hp * Uv[0] + bv[0];
    float zf = a1 + hp * Uv[1] + bv[1];
    float zg = a2 + hp * Uv[2] + bv[2];
    float zo = a3 + hp * Uv[3] + bv[3];
    float cn = sigm(zf) * c3[b] + sigm(zi) * tanh_(zg);
    c3[b] = cn;
    float hn = sigm(zo) * tanh_(cn);
    h3[b] = hn;
    gen[b * T_ + t] = hn;
  }
}

// final dense: disc[b,t] = hd2[b,:] . do_W + do_b
__global__ void k_dense(const u16* __restrict__ hd2, const float* __restrict__ wv,
                        const float* __restrict__ bs, float* __restrict__ disc, int t) {
  int b = blockIdx.x * 4 + (threadIdx.x >> 6);
  int lane = threadIdx.x & 63;
  float a = 0.f;
  for (int k = lane; k < H_; k += 64)
    a += bf2f(hd2[((size_t)b << 10) + k]) * wv[k];
  for (int off = 32; off; off >>= 1) a += __shfl_down(a, off);
  if (lane == 0) disc[b * T_ + t] = a + bs[0];
}

// merged steady-state small kernel: blocks 0..511 -> g3[t+1], 512..1023 -> dense[t]
__global__ void k_small(const u16* __restrict__ h2s, const float* __restrict__ W,
                        const float* __restrict__ Uv, const float* __restrict__ bv,
                        float* __restrict__ c3, float* __restrict__ h3,
                        float* __restrict__ gen, int tg,
                        const u16* __restrict__ hd2s, const float* __restrict__ wv,
                        const float* __restrict__ bs, float* __restrict__ disc, int td) {
  int lane = threadIdx.x & 63;
  if (blockIdx.x < 512) {
    int b = blockIdx.x * 4 + (threadIdx.x >> 6);
    float a0 = 0.f, a1 = 0.f, a2 = 0.f, a3 = 0.f;
    for (int k = lane; k < H_; k += 64) {
      float hv = bf2f(h2s[((size_t)b << 10) + k]);
      const f32x4 wv4 = *(const f32x4*)&W[k << 2];
      a0 += hv * wv4.x; a1 += hv * wv4.y; a2 += hv * wv4.z; a3 += hv * wv4.w;
    }
    for (int off = 32; off; off >>= 1) {
      a0 += __shfl_down(a0, off);
      a1 += __shfl_down(a1, off);
      a2 += __shfl_down(a2, off);
      a3 += __shfl_down(a3, off);
    }
    if (lane == 0) {
      float hp = h3[b];
      float zi = a0 + hp * Uv[0] + bv[0];
      float zf = a1 + hp * Uv[1] + bv[1];
      float zg = a2 + hp * Uv[2] + bv[2];
      float zo = a3 + hp * Uv[3] + bv[3];
      float cn = sigm(zf) * c3[b] + sigm(zi) * tanh_(zg);
      c3[b] = cn;
      float hn = sigm(zo) * tanh_(cn);
      h3[b] = hn;
      gen[b * T_ + tg] = hn;
    }
  } else {
    int b = (blockIdx.x - 512) * 4 + (threadIdx.x >> 6);
    float a = 0.f;
    for (int k = lane; k < H_; k += 64)
      a += bf2f(hd2s[((size_t)b << 10) + k]) * wv[k];
    for (int off = 32; off; off >>= 1) a += __shfl_down(a, off);
    if (lane == 0) disc[b * T_ + td] = a + bs[0];
  }
}

// -------------------- launcher --------------------
// Software pipeline: generator chain at step t+1 runs concurrently (same launch)
// with discriminator chain at step t. 3 launches/step instead of 6.
//   J1(t) = {g1[t+1], d1[t]}   J2(t) = {g2[t+1], d2[t]}   S(t) = {g3[t+1], dense[t]}

extern "C" void kernel_launch(void* const* d_in, const int* in_sizes, int n_in,
                              void* d_out, int out_size, void* d_ws, size_t ws_size,
                              hipStream_t stream) {
  const float* x   = (const float*)d_in[0];
  const float* g1W = (const float*)d_in[1];
  const float* g1U = (const float*)d_in[2];
  const float* g1b = (const float*)d_in[3];
  const float* g2W = (const float*)d_in[4];
  const float* g2U = (const float*)d_in[5];
  const float* g2b = (const float*)d_in[6];
  const float* g3W = (const float*)d_in[7];
  const float* g3U = (const float*)d_in[8];
  const float* g3b = (const float*)d_in[9];
  const float* d1W = (const float*)d_in[10];
  const float* d1U = (const float*)d_in[11];
  const float* d1b = (const float*)d_in[12];
  const float* d2W = (const float*)d_in[13];
  const float* d2U = (const float*)d_in[14];
  const float* d2b = (const float*)d_in[15];
  const float* doW = (const float*)d_in[16];
  const float* dob = (const float*)d_in[17];

  char* ws = (char*)d_ws;
  u16* xT    = (u16*)(ws + 0);            // 16,777,216
  u16* BT1   = (u16*)(ws + 16777216);     //  8,912,896  [4096][1088]
  u16* BT2   = (u16*)(ws + 25690112);     // 16,777,216  [4096][2048]
  u16* BTd1  = (u16*)(ws + 42467328);     //  8,388,608  [4096][1024]
  u16* BTd2  = (u16*)(ws + 50855936);     // 16,777,216  [4096][2048]
  float* pb1  = (float*)(ws + 67633152);
  float* pb2  = (float*)(ws + 67649536);
  float* pbd1 = (float*)(ws + 67665920);
  float* pbd2 = (float*)(ws + 67682304);
  float* pd1W = (float*)(ws + 67698688);
  const size_t Z0 = 67715072;             // zeroed region start
  float* c1  = (float*)(ws + Z0);
  float* c2  = (float*)(ws + Z0 + 8388608);
  float* cd1 = (float*)(ws + Z0 + 16777216);
  float* cd2 = (float*)(ws + Z0 + 25165824);
  u16* h1[2]  = {(u16*)(ws + Z0 + 33554432), (u16*)(ws + Z0 + 37748736)};
  u16* h2[2]  = {(u16*)(ws + Z0 + 41943040), (u16*)(ws + Z0 + 46137344)};
  u16* hd1[2] = {(u16*)(ws + Z0 + 50331648), (u16*)(ws + Z0 + 54525952)};
  u16* hd2[2] = {(u16*)(ws + Z0 + 58720256), (u16*)(ws + Z0 + 62914560)};
  float* c3 = (float*)(ws + Z0 + 67108864);
  float* h3 = (float*)(ws + Z0 + 67117056);
  const size_t ZBYTES = 67125248;

  // setup (re-done every launch: ws is poisoned before each timed call)
  k_transpose_x<<<32768, 256, 0, stream>>>(x, xT);
  k_build_bt<<<dim3(5, 4096), 256, 0, stream>>>(g1U, g1W, BT1, 1024, 1088);
  k_build_bt<<<dim3(8, 4096), 256, 0, stream>>>(g2U, g2W, BT2, 1024, 2048);
  k_build_bt<<<dim3(4, 4096), 256, 0, stream>>>(d1U, nullptr, BTd1, 1024, 1024);
  k_build_bt<<<dim3(8, 4096), 256, 0, stream>>>(d2U, d2W, BTd2, 1024, 2048);
  k_build_bias<<<16, 256, 0, stream>>>(g1b, g2b, d1b, d2b, d1W, pb1, pb2, pbd1, pbd2, pd1W);
  (void)hipMemsetAsync(ws + Z0, 0, ZBYTES, stream);

  float* gen = (float*)d_out;
  float* disc = gen + (size_t)B_ * T_;
  dim3 blk(256);
  dim3 grid1(16, 32), grid2(32, 32);

  // ---- prolog: g-chain step 0 (t=0: rp=0, wp=1) ----
  {
    GemmP pg1 = {h1[0], H_, 16, xT, I_, 1, BT1, 1088,
                 pb1, nullptr, nullptr, 0, c1, h1[1]};
    k_gemm<<<grid1, blk, 0, stream>>>(pg1);
    GemmP pg2 = {h2[0], H_, 16, h1[1], H_, 16, BT2, 2048,
                 pb2, nullptr, nullptr, 0, c2, h2[1]};
    k_gemm<<<grid1, blk, 0, stream>>>(pg2);
    k_g3<<<512, blk, 0, stream>>>(h2[1], g3W, g3U, g3b, c3, h3, gen, 0);
  }

  // ---- steady state: t = 0..62 ----
  for (int t = 0; t < 63; ++t) {
    int rg = (t + 1) & 1, wg = rg ^ 1;  // g-chain step t+1 parity
    int rd = t & 1, wd = rd ^ 1;        // d-chain step t parity
    // J1: g1[t+1] || d1[t]
    GemmP pg1 = {h1[rg], H_, 16, xT + (size_t)(t + 1) * B_ * I_, I_, 1, BT1, 1088,
                 pb1, nullptr, nullptr, 0, c1, h1[wg]};
    GemmP pd1 = {hd1[rd], H_, 16, nullptr, 0, 0, BTd1, 1024,
                 pbd1, pd1W, gen + t, T_, cd1, hd1[wd]};
    k_gemm2<<<grid2, blk, 0, stream>>>(pg1, pd1);
    // J2: g2[t+1] || d2[t]
    GemmP pg2 = {h2[rg], H_, 16, h1[wg], H_, 16, BT2, 2048,
                 pb2, nullptr, nullptr, 0, c2, h2[wg]};
    GemmP pd2 = {hd2[rd], H_, 16, hd1[wd], H_, 16, BTd2, 2048,
                 pbd2, nullptr, nullptr, 0, cd2, hd2[wd]};
    k_gemm2<<<grid2, blk, 0, stream>>>(pg2, pd2);
    // S: g3[t+1] || dense[t]
    k_small<<<1024, blk, 0, stream>>>(h2[wg], g3W, g3U, g3b, c3, h3, gen, t + 1,
                                      hd2[wd], doW, dob, disc, t);
  }

  // ---- epilog: d-chain step 63 (rd=1, wd=0) ----
  {
    GemmP pd1 = {hd1[1], H_, 16, nullptr, 0, 0, BTd1, 1024,
                 pbd1, pd1W, gen + 63, T_, cd1, hd1[0]};
    k_gemm<<<grid1, blk, 0, stream>>>(pd1);
    GemmP pd2 = {hd2[1], H_, 16, hd1[0], H_, 16, BTd2, 2048,
                 pbd2, nullptr, nullptr, 0, cd2, hd2[0]};
    k_gemm<<<grid1, blk, 0, stream>>>(pd2);
    k_dense<<<512, blk, 0, stream>>>(hd2[0], doW, dob, disc, 63);
  }
  (void)in_sizes; (void)n_in; (void)out_size; (void)ws_size;
}

// Round 10
// 13354.805 us; speedup vs baseline: 3.2364x; 1.0205x over previous
//
#include <hip/hip_runtime.h>

typedef unsigned short u16;
typedef __attribute__((ext_vector_type(8))) short short8;
typedef __attribute__((ext_vector_type(4))) float f32x4;

#define B_ 2048
#define T_ 64
#define I_ 64
#define H_ 1024
#define G_ 4096

__device__ __forceinline__ float bf2f(u16 v) {
  union { float f; unsigned u; } x; x.u = ((unsigned)v) << 16; return x.f;
}
__device__ __forceinline__ u16 f2bf(float f) {
  union { float f; unsigned u; } x; x.f = f;
  unsigned r = x.u + 0x7fffu + ((x.u >> 16) & 1u);
  return (u16)(r >> 16);
}
__device__ __forceinline__ float sigm(float x) { return 1.0f / (1.0f + __expf(-x)); }
__device__ __forceinline__ float tanh_(float x) { return 1.0f - 2.0f / (__expf(2.0f * x) + 1.0f); }

// Interleaved A-layout ("ilv"): element (m,k) of a [M][K] bf16 matrix lives at
//   ((m>>4)*(K/8) + (k>>3))*128 + (m&15)*8 + (k&7)
// = MFMA-A-fragment order: a wave's 8 frag loads per K-tile are each 1KB
// CONTIGUOUS global reads (16 fully-consumed 64B lines). A never touches LDS.

// -------------------- setup kernels --------------------

// x [B,T,I] fp32 -> xT [T][ilv(B,I)] bf16  (K8 = I/8 = 8)
__global__ void k_transpose_x(const float* __restrict__ x, u16* __restrict__ xT) {
  int idx = blockIdx.x * 256 + threadIdx.x;  // over B*T*I = 8388608
  if (idx >= B_ * T_ * I_) return;
  int i = idx & 63;
  int t = (idx >> 6) & 63;
  int b = idx >> 12;
  size_t dst = (size_t)t * B_ * I_ +
               ((size_t)((b >> 4) * 8 + (i >> 3)) << 7) + ((b & 15) << 3) + (i & 7);
  xT[dst] = f2bf(x[idx]);
}

// Build BT [4096][K] bf16 (row-major, unchanged): rows are permuted output cols
// n' = 4*unit + gate; k<K0 from U, k>=K0 from W. Orig col j = gate*1024 + unit.
__global__ void k_build_bt(const float* __restrict__ U, const float* __restrict__ W,
                           u16* __restrict__ BT, int K0, int K) {
  int n = blockIdx.y;
  int k = blockIdx.x * 256 + threadIdx.x;
  if (k >= K) return;
  int j = (n & 3) * 1024 + (n >> 2);
  float v = (k < K0) ? U[(size_t)k * G_ + j] : W[(size_t)(k - K0) * G_ + j];
  BT[(size_t)n * K + k] = f2bf(v);
}

__global__ void k_build_bias(const float* __restrict__ b1, const float* __restrict__ b2,
                             const float* __restrict__ bd1, const float* __restrict__ bd2,
                             const float* __restrict__ d1W,
                             float* __restrict__ p1, float* __restrict__ p2,
                             float* __restrict__ pd1, float* __restrict__ pd2,
                             float* __restrict__ pd1W) {
  int n = blockIdx.x * 256 + threadIdx.x;
  if (n >= G_) return;
  int j = (n & 3) * 1024 + (n >> 2);
  p1[n] = b1[j]; p2[n] = b2[j]; pd1[n] = bd1[j]; pd2[n] = bd2[j];
  pd1W[n] = d1W[j];
}

// -------------------- fused GEMM + LSTM cell --------------------

struct GemmP {
  const u16* A0; int ka0, kt0;   // A0 in ilv layout, K dim = ka0
  const u16* A1; int ka1, kt1;   // A1 in ilv layout (optional)
  const u16* BT; int ldb;        // B row-major [4096][ldb]
  const float* biasp;
  const float* evec;
  const float* escal; int estride;
  float* cst; u16* hout;         // cst plain [m][1024]; hout written in ilv
};

// DS pipe was the round-7 bottleneck (192KB/CU-phase ≈ 1900cy vs 155cy MFMA).
// Now: A read DIRECT from global in ilv layout (register double-buffered, 1
// phase ahead, L1 catches the 2x wave-pair reuse); only B goes through LDS
// (dbuf 2x16KB). DS per block-phase 96KB -> 48KB. No global_load_lds anywhere
// (gfx950 LDS-DMA generates ~2B/B phantom EA-write traffic; proven round 6).

#define LOADB(kt_, tb) do {                                                   \
    int kk_ = (kt_);                                                          \
    _Pragma("unroll")                                                         \
    for (int s = 0; s < 4; ++s) tb[s] = *(const short8*)(pB[s] + (size_t)kk_ * 64); \
  } while (0)

#define WRITEB(tb, SOFF) do {                                                 \
    _Pragma("unroll")                                                         \
    for (int s = 0; s < 4; ++s) *(short8*)&smem[(SOFF) + wpos[s]] = tb[s];    \
  } while (0)

// A-frags for K-tile kt_: fa[i*2+ks] = A[(mb4+i) tile][chunk kt_*8+ks*4+q], 16B/lane
#define LOADA(kt_, fa) do {                                                   \
    int kk_ = (kt_);                                                          \
    if (kk_ < p.kt0) {                                                        \
      size_t o_ = (size_t)kk_ * 1024;                                         \
      _Pragma("unroll")                                                       \
      for (int i = 0; i < 4; ++i) {                                           \
        fa[i * 2] = *(const short8*)(baseA0[i] + o_);                         \
        fa[i * 2 + 1] = *(const short8*)(baseA0[i] + o_ + 512);               \
      }                                                                       \
    } else {                                                                  \
      size_t o_ = (size_t)(kk_ - p.kt0) * 1024;                               \
      _Pragma("unroll")                                                       \
      for (int i = 0; i < 4; ++i) {                                           \
        fa[i * 2] = *(const short8*)(baseA1[i] + o_);                         \
        fa[i * 2 + 1] = *(const short8*)(baseA1[i] + o_ + 512);               \
      }                                                                       \
    }                                                                         \
  } while (0)

#define COMPUTET(SOFF, fa) do {                                               \
    __builtin_amdgcn_s_setprio(1);                                            \
    _Pragma("unroll")                                                         \
    for (int ks = 0; ks < 2; ++ks) {                                          \
      const int sw = ((((ks << 2) + q) ^ l7) << 3);                           \
      short8 bfv[4];                                                          \
      _Pragma("unroll")                                                       \
      for (int j = 0; j < 4; ++j) bfv[j] = *(const short8*)&smem[(SOFF) + boffr[j] + sw]; \
      _Pragma("unroll")                                                       \
      for (int i = 0; i < 4; ++i)                                             \
        _Pragma("unroll")                                                     \
        for (int j = 0; j < 4; ++j)                                           \
          acc[i][j] = __builtin_amdgcn_mfma_f32_16x16x32_bf16(fa[i * 2 + ks], bfv[j], acc[i][j], 0, 0, 0); \
    }                                                                         \
    __builtin_amdgcn_s_setprio(0);                                            \
  } while (0)

#define KBAR() do {                                                           \
    asm volatile("s_waitcnt lgkmcnt(0)" ::: "memory");                        \
    __builtin_amdgcn_s_barrier();                                             \
  } while (0)

__device__ __forceinline__ void gemm_body(u16* smem, const GemmP& p, int m0, int n0) {
  const int tid = threadIdx.x;
  const int lane = tid & 63;
  const int w = tid >> 6;
  const int KT = p.kt0 + p.kt1;

  const int wm = (w >> 1) << 6, wn = (w & 1) << 6;
  const int q = lane >> 4, l15 = lane & 15, l7 = lane & 7;

  // B staging: thread covers B row rs = s*32 + tid/8, chunk c_ = tid&7 (linear
  // global); LDS chunk ch of row rs holds global chunk ch^(rs&7) (XOR on write)
  const int r_ = tid >> 3, c_ = tid & 7;
  const u16* pB[4];
  int wpos[4];
#pragma unroll
  for (int s = 0; s < 4; ++s) {
    int rs = (s << 5) + r_;
    pB[s] = p.BT + (size_t)(n0 + rs) * p.ldb + (c_ << 3);
    wpos[s] = (rs << 6) + ((c_ ^ (rs & 7)) << 3);
  }

  // A direct-from-global bases (ilv layout)
  const int mb4 = (m0 + wm) >> 4;
  const int K80 = p.ka0 >> 3;
  const int K81 = p.A1 ? (p.ka1 >> 3) : K80;
  const u16* baseA0[4]; const u16* baseA1[4];
#pragma unroll
  for (int i = 0; i < 4; ++i) {
    baseA0[i] = p.A0 + (((size_t)(mb4 + i) * K80 + q) << 7) + (l15 << 3);
    baseA1[i] = p.A1 ? (p.A1 + (((size_t)(mb4 + i) * K81 + q) << 7) + (l15 << 3))
                     : baseA0[i];
  }

  f32x4 acc[4][4];
#pragma unroll
  for (int i = 0; i < 4; ++i)
#pragma unroll
    for (int j = 0; j < 4; ++j) acc[i][j] = (f32x4){0.f, 0.f, 0.f, 0.f};

  int boffr[4];
#pragma unroll
  for (int i = 0; i < 4; ++i) boffr[i] = (wn + (i << 4) + l15) << 6;

  short8 afA[8], afB[8], sb0[4], sb1[4];

  // prologue: B tiles 0,1 -> reg; A frags tile 0 -> reg; B tile 0 -> buf0
  LOADB(0, sb0);
  LOADB(1, sb1);
  LOADA(0, afA);
  WRITEB(sb0, 0);
  KBAR();

  for (int kt = 0; kt < KT; kt += 2) {
    // even phase: compute (buf0, afA) for tile kt
    if (kt + 1 < KT) LOADA(kt + 1, afB);
    if (kt + 2 < KT) LOADB(kt + 2, sb0);
    if (kt + 1 < KT) WRITEB(sb1, 8192);
    COMPUTET(0, afA);
    KBAR();
    if (kt + 1 >= KT) break;
    // odd phase: compute (buf1, afB) for tile kt+1
    if (kt + 2 < KT) LOADA(kt + 2, afA);
    if (kt + 3 < KT) LOADB(kt + 3, sb1);
    if (kt + 2 < KT) WRITEB(sb0, 0);
    COMPUTET(8192, afB);
    KBAR();
  }

  // ---- fused LSTM-cell epilogue (LDS reshuffle: C-layout -> per-lane 4 gates) ----
  __syncthreads();
  float* ep = (float*)smem + w * 1280;  // per-wave [64][20] fp32 region
  const int ul = lane & 3, ml = lane >> 2;
  const int ubase = (n0 >> 2) + (wn >> 2);
#pragma unroll 1
  for (int tj = 0; tj < 4; ++tj) {
#pragma unroll
    for (int ti = 0; ti < 4; ++ti)
#pragma unroll
      for (int v = 0; v < 4; ++v)
        ep[((ti << 4) + (q << 2) + v) * 20 + l15] = acc[ti][tj][v];
    __syncthreads();
#pragma unroll
    for (int pp = 0; pp < 4; ++pp) {
      int row = ml + (pp << 4);
      f32x4 z = *(const f32x4*)&ep[row * 20 + (ul << 2)];
      int gm = m0 + wm + row;
      int gu = ubase + (tj << 2) + ul;
      const f32x4 bb = *(const f32x4*)&p.biasp[gu << 2];
      z.x += bb.x; z.y += bb.y; z.z += bb.z; z.w += bb.w;
      if (p.evec) {  // d1: + gen[m] * d1_W[n']  (K=1 input folded here, fp32)
        float gs = p.escal[(size_t)gm * p.estride];
        const f32x4 ev = *(const f32x4*)&p.evec[gu << 2];
        z.x += gs * ev.x; z.y += gs * ev.y; z.z += gs * ev.z; z.w += gs * ev.w;
      }
      float ig = sigm(z.x), fg = sigm(z.y), gg = tanh_(z.z), og = sigm(z.w);
      size_t ci = ((size_t)gm << 10) + gu;
      float cn = fg * p.cst[ci] + ig * gg;
      p.cst[ci] = cn;
      // hout in ilv layout (K8 = 1024/8 = 128)
      size_t hi = ((size_t)((gm >> 4) * 128 + (gu >> 3)) << 7) + ((gm & 15) << 3) + (gu & 7);
      p.hout[hi] = f2bf(og * tanh_(cn));
    }
    __syncthreads();
  }
}

// single-problem wrapper, 512 blocks. XCD-local: id&7 = xcd; each XCD owns
// 4 contiguous by x all 16 bx -> per-K-step slice L2-resident.
__global__ __launch_bounds__(256, 2) void k_gemm(GemmP p) {
  __shared__ u16 smem[16384];  // 32 KB: B dbuf 2x16KB
  int id = blockIdx.y * 16 + blockIdx.x;
  int xcd = id & 7, slot = id >> 3;
  int by = (xcd << 2) + (slot >> 4);
  int bx = slot & 15;
  gemm_body(smem, p, bx << 7, by << 7);
}

// paired wrapper: two INDEPENDENT problems; XCD parity selects problem.
__global__ __launch_bounds__(256, 2) void k_gemm2(GemmP pa, GemmP pb) {
  __shared__ u16 smem[16384];  // 32 KB
  int id = blockIdx.y * 32 + blockIdx.x;
  int xcd = id & 7, slot = id >> 3;
  const GemmP& p = (xcd & 1) ? pb : pa;
  int by = ((xcd >> 1) << 3) + (slot >> 4);
  int bx = slot & 15;
  gemm_body(smem, p, bx << 7, by << 7);
}

// -------------------- small kernels (h inputs in ilv layout) --------------------

// g3: LSTM with H=1. One wave per batch row; lane covers chunks ch, ch+64.
__global__ void k_g3(const u16* __restrict__ h2, const float* __restrict__ W,
                     const float* __restrict__ Uv, const float* __restrict__ bv,
                     float* __restrict__ c3, float* __restrict__ h3,
                     float* __restrict__ gen, int t) {
  int b = blockIdx.x * 4 + (threadIdx.x >> 6);
  int lane = threadIdx.x & 63;
  float a0 = 0.f, a1 = 0.f, a2 = 0.f, a3 = 0.f;
  for (int ch = lane; ch < 128; ch += 64) {
    short8 v = *(const short8*)&h2[((size_t)((b >> 4) * 128 + ch) << 7) + ((b & 15) << 3)];
#pragma unroll
    for (int e = 0; e < 8; ++e) {
      float hv = bf2f((u16)v[e]);
      const f32x4 wv = *(const f32x4*)&W[(ch * 8 + e) << 2];
      a0 += hv * wv.x; a1 += hv * wv.y; a2 += hv * wv.z; a3 += hv * wv.w;
    }
  }
  for (int off = 32; off; off >>= 1) {
    a0 += __shfl_down(a0, off);
    a1 += __shfl_down(a1, off);
    a2 += __shfl_down(a2, off);
    a3 += __shfl_down(a3, off);
  }
  if (lane == 0) {
    float hp = h3[b];
    float zi = a0 + hp * Uv[0] + bv[0];
    float zf = a1 + hp * Uv[1] + bv[1];
    float zg = a2 + hp * Uv[2] + bv[2];
    float zo = a3 + hp * Uv[3] + bv[3];
    float cn = sigm(zf) * c3[b] + sigm(zi) * tanh_(zg);
    c3[b] = cn;
    float hn = sigm(zo) * tanh_(cn);
    h3[b] = hn;
    gen[b * T_ + t] = hn;
  }
}

// final dense: disc[b,t] = hd2[b,:] . do_W + do_b
__global__ void k_dense(const u16* __restrict__ hd2, const float* __restrict__ wv,
                        const float* __restrict__ bs, float* __restrict__ disc, int t) {
  int b = blockIdx.x * 4 + (threadIdx.x >> 6);
  int lane = threadIdx.x & 63;
  float a = 0.f;
  for (int ch = lane; ch < 128; ch += 64) {
    short8 v = *(const short8*)&hd2[((size_t)((b >> 4) * 128 + ch) << 7) + ((b & 15) << 3)];
#pragma unroll
    for (int e = 0; e < 8; ++e) a += bf2f((u16)v[e]) * wv[ch * 8 + e];
  }
  for (int off = 32; off; off >>= 1) a += __shfl_down(a, off);
  if (lane == 0) disc[b * T_ + t] = a + bs[0];
}

// merged steady-state small kernel: blocks 0..511 -> g3[t+1], 512..1023 -> dense[t]
__global__ void k_small(const u16* __restrict__ h2s, const float* __restrict__ W,
                        const float* __restrict__ Uv, const float* __restrict__ bv,
                        float* __restrict__ c3, float* __restrict__ h3,
                        float* __restrict__ gen, int tg,
                        const u16* __restrict__ hd2s, const float* __restrict__ wv,
                        const float* __restrict__ bs, float* __restrict__ disc, int td) {
  int lane = threadIdx.x & 63;
  if (blockIdx.x < 512) {
    int b = blockIdx.x * 4 + (threadIdx.x >> 6);
    float a0 = 0.f, a1 = 0.f, a2 = 0.f, a3 = 0.f;
    for (int ch = lane; ch < 128; ch += 64) {
      short8 v = *(const short8*)&h2s[((size_t)((b >> 4) * 128 + ch) << 7) + ((b & 15) << 3)];
#pragma unroll
      for (int e = 0; e < 8; ++e) {
        float hv = bf2f((u16)v[e]);
        const f32x4 wv4 = *(const f32x4*)&W[(ch * 8 + e) << 2];
        a0 += hv * wv4.x; a1 += hv * wv4.y; a2 += hv * wv4.z; a3 += hv * wv4.w;
      }
    }
    for (int off = 32; off; off >>= 1) {
      a0 += __shfl_down(a0, off);
      a1 += __shfl_down(a1, off);
      a2 += __shfl_down(a2, off);
      a3 += __shfl_down(a3, off);
    }
    if (lane == 0) {
      float hp = h3[b];
      float zi = a0 + hp * Uv[0] + bv[0];
      float zf = a1 + hp * Uv[1] + bv[1];
      float zg = a2 + hp * Uv[2] + bv[2];
      float zo = a3 + hp * Uv[3] + bv[3];
      float cn = sigm(zf) * c3[b] + sigm(zi) * tanh_(zg);
      c3[b] = cn;
      float hn = sigm(zo) * tanh_(cn);
      h3[b] = hn;
      gen[b * T_ + tg] = hn;
    }
  } else {
    int b = (blockIdx.x - 512) * 4 + (threadIdx.x >> 6);
    float a = 0.f;
    for (int ch = lane; ch < 128; ch += 64) {
      short8 v = *(const short8*)&hd2s[((size_t)((b >> 4) * 128 + ch) << 7) + ((b & 15) << 3)];
#pragma unroll
      for (int e = 0; e < 8; ++e) a += bf2f((u16)v[e]) * wv[ch * 8 + e];
    }
    for (int off = 32; off; off >>= 1) a += __shfl_down(a, off);
    if (lane == 0) disc[b * T_ + td] = a + bs[0];
  }
}

// -------------------- launcher --------------------
// Software pipeline: generator chain (step t+1) || discriminator chain (step t).
//   J1(t) = {g1[t+1], d1[t]}   J2(t) = {g2[t+1], d2[t]}   S(t) = {g3[t+1], dense[t]}

extern "C" void kernel_launch(void* const* d_in, const int* in_sizes, int n_in,
                              void* d_out, int out_size, void* d_ws, size_t ws_size,
                              hipStream_t stream) {
  const float* x   = (const float*)d_in[0];
  const float* g1W = (const float*)d_in[1];
  const float* g1U = (const float*)d_in[2];
  const float* g1b = (const float*)d_in[3];
  const float* g2W = (const float*)d_in[4];
  const float* g2U = (const float*)d_in[5];
  const float* g2b = (const float*)d_in[6];
  const float* g3W = (const float*)d_in[7];
  const float* g3U = (const float*)d_in[8];
  const float* g3b = (const float*)d_in[9];
  const float* d1W = (const float*)d_in[10];
  const float* d1U = (const float*)d_in[11];
  const float* d1b = (const float*)d_in[12];
  const float* d2W = (const float*)d_in[13];
  const float* d2U = (const float*)d_in[14];
  const float* d2b = (const float*)d_in[15];
  const float* doW = (const float*)d_in[16];
  const float* dob = (const float*)d_in[17];

  char* ws = (char*)d_ws;
  u16* xT    = (u16*)(ws + 0);            // 16,777,216
  u16* BT1   = (u16*)(ws + 16777216);     //  8,912,896  [4096][1088]
  u16* BT2   = (u16*)(ws + 25690112);     // 16,777,216  [4096][2048]
  u16* BTd1  = (u16*)(ws + 42467328);     //  8,388,608  [4096][1024]
  u16* BTd2  = (u16*)(ws + 50855936);     // 16,777,216  [4096][2048]
  float* pb1  = (float*)(ws + 67633152);
  float* pb2  = (float*)(ws + 67649536);
  float* pbd1 = (float*)(ws + 67665920);
  float* pbd2 = (float*)(ws + 67682304);
  float* pd1W = (float*)(ws + 67698688);
  const size_t Z0 = 67715072;             // zeroed region start
  float* c1  = (float*)(ws + Z0);
  float* c2  = (float*)(ws + Z0 + 8388608);
  float* cd1 = (float*)(ws + Z0 + 16777216);
  float* cd2 = (float*)(ws + Z0 + 25165824);
  u16* h1[2]  = {(u16*)(ws + Z0 + 33554432), (u16*)(ws + Z0 + 37748736)};
  u16* h2[2]  = {(u16*)(ws + Z0 + 41943040), (u16*)(ws + Z0 + 46137344)};
  u16* hd1[2] = {(u16*)(ws + Z0 + 50331648), (u16*)(ws + Z0 + 54525952)};
  u16* hd2[2] = {(u16*)(ws + Z0 + 58720256), (u16*)(ws + Z0 + 62914560)};
  float* c3 = (float*)(ws + Z0 + 67108864);
  float* h3 = (float*)(ws + Z0 + 67117056);
  const size_t ZBYTES = 67125248;

  // setup (re-done every launch: ws is poisoned before each timed call)
  k_transpose_x<<<32768, 256, 0, stream>>>(x, xT);
  k_build_bt<<<dim3(5, 4096), 256, 0, stream>>>(g1U, g1W, BT1, 1024, 1088);
  k_build_bt<<<dim3(8, 4096), 256, 0, stream>>>(g2U, g2W, BT2, 1024, 2048);
  k_build_bt<<<dim3(4, 4096), 256, 0, stream>>>(d1U, nullptr, BTd1, 1024, 1024);
  k_build_bt<<<dim3(8, 4096), 256, 0, stream>>>(d2U, d2W, BTd2, 1024, 2048);
  k_build_bias<<<16, 256, 0, stream>>>(g1b, g2b, d1b, d2b, d1W, pb1, pb2, pbd1, pbd2, pd1W);
  (void)hipMemsetAsync(ws + Z0, 0, ZBYTES, stream);

  float* gen = (float*)d_out;
  float* disc = gen + (size_t)B_ * T_;
  dim3 blk(256);
  dim3 grid1(16, 32), grid2(32, 32);

  // ---- prolog: g-chain step 0 (t=0: rp=0, wp=1) ----
  {
    GemmP pg1 = {h1[0], H_, 16, xT, I_, 1, BT1, 1088,
                 pb1, nullptr, nullptr, 0, c1, h1[1]};
    k_gemm<<<grid1, blk, 0, stream>>>(pg1);
    GemmP pg2 = {h2[0], H_, 16, h1[1], H_, 16, BT2, 2048,
                 pb2, nullptr, nullptr, 0, c2, h2[1]};
    k_gemm<<<grid1, blk, 0, stream>>>(pg2);
    k_g3<<<512, blk, 0, stream>>>(h2[1], g3W, g3U, g3b, c3, h3, gen, 0);
  }

  // ---- steady state: t = 0..62 ----
  for (int t = 0; t < 63; ++t) {
    int rg = (t + 1) & 1, wg = rg ^ 1;  // g-chain step t+1 parity
    int rd = t & 1, wd = rd ^ 1;        // d-chain step t parity
    // J1: g1[t+1] || d1[t]
    GemmP pg1 = {h1[rg], H_, 16, xT + (size_t)(t + 1) * B_ * I_, I_, 1, BT1, 1088,
                 pb1, nullptr, nullptr, 0, c1, h1[wg]};
    GemmP pd1 = {hd1[rd], H_, 16, nullptr, 0, 0, BTd1, 1024,
                 pbd1, pd1W, gen + t, T_, cd1, hd1[wd]};
    k_gemm2<<<grid2, blk, 0, stream>>>(pg1, pd1);
    // J2: g2[t+1] || d2[t]
    GemmP pg2 = {h2[rg], H_, 16, h1[wg], H_, 16, BT2, 2048,
                 pb2, nullptr, nullptr, 0, c2, h2[wg]};
    GemmP pd2 = {hd2[rd], H_, 16, hd1[wd], H_, 16, BTd2, 2048,
                 pbd2, nullptr, nullptr, 0, cd2, hd2[wd]};
    k_gemm2<<<grid2, blk, 0, stream>>>(pg2, pd2);
    // S: g3[t+1] || dense[t]
    k_small<<<1024, blk, 0, stream>>>(h2[wg], g3W, g3U, g3b, c3, h3, gen, t + 1,
                                      hd2[wd], doW, dob, disc, t);
  }

  // ---- epilog: d-chain step 63 (rd=1, wd=0) ----
  {
    GemmP pd1 = {hd1[1], H_, 16, nullptr, 0, 0, BTd1, 1024,
                 pbd1, pd1W, gen + 63, T_, cd1, hd1[0]};
    k_gemm<<<grid1, blk, 0, stream>>>(pd1);
    GemmP pd2 = {hd2[1], H_, 16, hd1[0], H_, 16, BTd2, 2048,
                 pbd2, nullptr, nullptr, 0, cd2, hd2[0]};
    k_gemm<<<grid1, blk, 0, stream>>>(pd2);
    k_dense<<<512, blk, 0, stream>>>(hd2[0], doW, dob, disc, 63);
  }
  (void)in_sizes; (void)n_in; (void)out_size; (void)ws_size;
}